// Round 8
// baseline (466.106 us; speedup 1.0000x reference)
//
#include <hip/hip_runtime.h>
#include <hip/hip_bf16.h>

#define B 8
#define N 8192
#define E 65536
#define FIN 64
#define H 128
#define OUTD 256
#define NLAYER 3
#define EPS 1e-5f
#define PCHUNK 64
#define PNODES (N / PCHUNK)
#define TM 32
#define PADF 68
#define NNODE (B * N)            // 65536 rows
#define KSTEPS 16                // 4 groups x 4 k-steps of K=32
#define BPL (KSTEPS * 8 * 512)   // Bp ushort elems per layer
#define ELLW 48                  // max incoming edges/node (Poisson(8): P(>48) ~ 1e-25)

typedef float f32x4 __attribute__((ext_vector_type(4)));
typedef __bf16 bf16x8 __attribute__((ext_vector_type(8)));

__device__ __forceinline__ float b2f(unsigned short u) {
    union { float f; unsigned int i; } c; c.i = ((unsigned int)u) << 16; return c.f;
}
__device__ __forceinline__ unsigned short f2b(float f) {
    __hip_bfloat16 h = __float2bfloat16(f);          // RTNE
    return *reinterpret_cast<unsigned short*>(&h);
}

// ---------------- weight pre-pack: fragment-ordered split-bf16 B' ----------------
// groups: 0 xh*sWhi, 1 xl*sWhi, 2 xh*sWlo, 3 nh*nWhi
__global__ void k_prepB(const float* __restrict__ selfW, const float* __restrict__ neighW,
                        unsigned short* __restrict__ Bp) {
    const int idx = blockIdx.x;            // l*KSTEPS*8 + s*8 + t
    const int t = idx & 7;
    const int s = (idx >> 3) % KSTEPS;
    const int l = idx / (KSTEPS * 8);
    const int lane = threadIdx.x;
    const int quad = lane >> 4, col = lane & 15;
    const int g = s >> 2;
    const float* W = ((g < 3) ? selfW : neighW) + (size_t)l * H * H;
    const bool lo = (g == 2);
    const int n = t * 16 + col;
    unsigned short* dst = Bp + ((size_t)(l * KSTEPS + s) * 8 + t) * 512 + lane * 8;
    #pragma unroll
    for (int j = 0; j < 8; ++j) {
        const int kk = (s & 3) * 32 + quad * 8 + j;
        const float w = W[kk * H + n];
        const unsigned short hi = f2b(w);
        dst[j] = lo ? f2b(w - b2f(hi)) : hi;
    }
}

// ---------------- input projection -> split-bf16 x ----------------
__global__ __launch_bounds__(256) void k_inproj3(const float* __restrict__ feats,
                                                 const float* __restrict__ W,
                                                 const float* __restrict__ bias,
                                                 unsigned short* __restrict__ xh,
                                                 unsigned short* __restrict__ xl) {
    __shared__ float fs[TM * PADF];
    __shared__ float wB[FIN * H];
    const int tid = threadIdx.x;
    const int i = tid >> 5, j = tid & 31;
    const int row0 = blockIdx.x * TM;

    for (int v = tid; v < TM * (FIN / 4); v += 256) {
        int n = v >> 4, kq = (v & 15) << 2;
        *(float4*)&fs[n * PADF + kq] = *(const float4*)&feats[(size_t)(row0 + n) * FIN + kq];
    }
    for (int v = tid; v < FIN * H / 4; v += 256)
        *(float4*)&wB[v * 4] = *(const float4*)&W[v * 4];
    __syncthreads();

    float acc[4][4] = {};
    #pragma unroll
    for (int k4 = 0; k4 < FIN / 4; ++k4) {
        float4 xa[4];
        #pragma unroll
        for (int a = 0; a < 4; ++a)
            xa[a] = *(const float4*)&fs[(i * 4 + a) * PADF + k4 * 4];
        #pragma unroll
        for (int t = 0; t < 4; ++t) {
            float4 bs = *(const float4*)&wB[(k4 * 4 + t) * H + (j << 2)];
            #pragma unroll
            for (int a = 0; a < 4; ++a) {
                const float va = ((const float*)&xa[a])[t];
                acc[a][0] = fmaf(va, bs.x, acc[a][0]);
                acc[a][1] = fmaf(va, bs.y, acc[a][1]);
                acc[a][2] = fmaf(va, bs.z, acc[a][2]);
                acc[a][3] = fmaf(va, bs.w, acc[a][3]);
            }
        }
    }
    const float4 bv = *(const float4*)&bias[j << 2];
    #pragma unroll
    for (int a = 0; a < 4; ++a) {
        float o[4];
        o[0] = fmaxf(acc[a][0] + bv.x, 0.f);
        o[1] = fmaxf(acc[a][1] + bv.y, 0.f);
        o[2] = fmaxf(acc[a][2] + bv.z, 0.f);
        o[3] = fmaxf(acc[a][3] + bv.w, 0.f);
        ushort4 h4, l4;
        h4.x = f2b(o[0]); l4.x = f2b(o[0] - b2f(h4.x));
        h4.y = f2b(o[1]); l4.y = f2b(o[1] - b2f(h4.y));
        h4.z = f2b(o[2]); l4.z = f2b(o[2] - b2f(h4.z));
        h4.w = f2b(o[3]); l4.w = f2b(o[3] - b2f(h4.w));
        const size_t a0 = (size_t)(row0 + i * 4 + a) * H + (j << 2);
        *(ushort4*)&xh[a0] = h4;
        *(ushort4*)&xl[a0] = l4;
    }
}

// ---------------- ELL build: one fill pass (ecnt pre-zeroed) ----------------
__global__ void k_fill_ell(const int* __restrict__ ei, const float* __restrict__ emask,
                           int* __restrict__ ecnt, int2* __restrict__ ell) {
    const int ge = blockIdx.x * 256 + threadIdx.x;       // b*E + e
    const float m = emask[ge];
    if (m > 0.f) {
        const int b = ge >> 16, e = ge & 0xFFFF;
        const int tgt = ei[(b * 2 + 1) * E + e];
        const int src = ei[(b * 2) * E + e];
        const int r = b * N + tgt;
        const int p = atomicAdd(&ecnt[r], 1);
        if (p < ELLW) {
            int2 v; v.x = b * N + src; v.y = __float_as_int(m);
            ell[(size_t)r * ELLW + p] = v;
        }
    }
}

// ---------------- fused gather + layer: 32 rows/block, 2048 blocks, batch<->XCD pinned ----------------
// Phase 1: 4 waves x 8 rows gather neighbor means -> LDS (bf16, pitch 136 shorts).
// Phase 2: MFMA dual GEMM (groups xh*sWhi, xl*sWhi, xh*sWlo, nh*nWhi) + bias/relu/LN/mask.
// Out-of-place (xin -> xout), so no in-place hazards.
__global__ __launch_bounds__(256) void k_fused(const unsigned short* __restrict__ xinh,
                                               const unsigned short* __restrict__ xinl,
                                               const int* __restrict__ ecnt,
                                               const int2* __restrict__ ell,
                                               const unsigned short* __restrict__ Bp,
                                               const float* __restrict__ sb,
                                               const float* __restrict__ nb,
                                               const float* __restrict__ lng,
                                               const float* __restrict__ lnb,
                                               const float* __restrict__ nmask,
                                               unsigned short* __restrict__ oxh,
                                               unsigned short* __restrict__ oxl) {
    __shared__ __align__(16) unsigned short nh_s[32 * 136];   // 32 rows, pitch 136 (2-way banks, free)
    __shared__ float lsum[2][32];
    __shared__ float lsq[2][32];

    const int tid = threadIdx.x;
    const int wv = tid >> 6, lane = tid & 63;
    const int quad = lane >> 4, col = lane & 15;
    const int u = blockIdx.x;
    const int b = u & 7;                        // batch == home XCD
    const int row0 = b * N + (u >> 3) * 32;

    // ---- phase 1: gather means for rows [row0, row0+32), wave wv owns local rows wv*8..+7 ----
    {
        const unsigned int* xh32 = (const unsigned int*)xinh;
        int cnts[8];
        #pragma unroll
        for (int rr = 0; rr < 8; ++rr)
            cnts[rr] = min(ecnt[row0 + wv * 8 + rr], ELLW);
        int sv[8]; float mv[8];
        #pragma unroll
        for (int rr = 0; rr < 8; ++rr) {
            sv[rr] = 0; mv[rr] = 0.f;
            if (lane < cnts[rr]) {
                const int2 ev = ell[(size_t)(row0 + wv * 8 + rr) * ELLW + lane];
                sv[rr] = ev.x; mv[rr] = __int_as_float(ev.y);
            }
        }
        #pragma unroll
        for (int rr = 0; rr < 8; ++rr) {
            const int rl = wv * 8 + rr;
            float a0 = 0.f, a1 = 0.f, c = 0.f;
            const int cnt = cnts[rr];
            for (int jj = 0; jj < cnt; ++jj) {
                const int src = __shfl(sv[rr], jj);
                const float m = __shfl(mv[rr], jj);
                const unsigned int uu = xh32[(size_t)src * 64 + lane];
                union { unsigned int i; float f; } lo, hi;
                lo.i = uu << 16;
                hi.i = uu & 0xFFFF0000u;
                a0 = fmaf(lo.f, m, a0);
                a1 = fmaf(hi.f, m, a1);
                c += m;
            }
            const float inv = 1.f / fmaxf(c, 1.f);
            ((unsigned int*)nh_s)[rl * 68 + lane] =
                (unsigned int)f2b(a0 * inv) | ((unsigned int)f2b(a1 * inv) << 16);
        }
    }
    __syncthreads();

    // ---- phase 2: MFMA. wave = (mw, nw): m-tile mw (16 rows), n-tiles nw*4..+3 ----
    const int mw = wv >> 1, nw = wv & 1;
    const size_t abase = (size_t)(row0 + mw * 16 + col) * H + quad * 8;
    const int arl = (mw * 16 + col) * 136 + quad * 8;       // LDS A base (shorts)

    f32x4 acc[4] = {};

    bf16x8 aC = *(const bf16x8*)&xinh[abase];
    bf16x8 bC[4];
    #pragma unroll
    for (int nt = 0; nt < 4; ++nt)
        bC[nt] = *(const bf16x8*)&Bp[((size_t)(nw * 4 + nt)) * 512 + lane * 8];

    #pragma unroll
    for (int s = 0; s < KSTEPS; ++s) {
        bf16x8 aN, bN[4];
        if (s + 1 < KSTEPS) {
            const int s1 = s + 1, g1 = s1 >> 2;
            const int ko = (s1 & 3) * 32;
            if (g1 == 3)
                aN = *(const bf16x8*)&nh_s[arl + ko];
            else {
                const unsigned short* A = (g1 == 1) ? xinl : xinh;
                aN = *(const bf16x8*)&A[abase + ko];
            }
            #pragma unroll
            for (int nt = 0; nt < 4; ++nt)
                bN[nt] = *(const bf16x8*)&Bp[((size_t)s1 * 8 + nw * 4 + nt) * 512 + lane * 8];
        }
        #pragma unroll
        for (int nt = 0; nt < 4; ++nt)
            acc[nt] = __builtin_amdgcn_mfma_f32_16x16x32_bf16(aC, bC[nt], acc[nt], 0, 0, 0);
        aC = aN;
        #pragma unroll
        for (int nt = 0; nt < 4; ++nt) bC[nt] = bN[nt];
    }

    // bias + relu (C/D: row = quad*4 + r, col = lane&15; h = (nw*4+nt)*16 + col)
    float sbv[4], nbv[4], gv[4], bbv[4];
    #pragma unroll
    for (int nt = 0; nt < 4; ++nt) {
        const int hh = (nw * 4 + nt) * 16 + col;
        sbv[nt] = sb[hh]; nbv[nt] = nb[hh]; gv[nt] = lng[hh]; bbv[nt] = lnb[hh];
    }
    #pragma unroll
    for (int nt = 0; nt < 4; ++nt)
        #pragma unroll
        for (int r = 0; r < 4; ++r)
            acc[nt][r] = fmaxf(acc[nt][r] + sbv[nt] + nbv[nt], 0.f);

    // LN partials
    #pragma unroll
    for (int r = 0; r < 4; ++r) {
        float p = 0.f, q = 0.f;
        #pragma unroll
        for (int nt = 0; nt < 4; ++nt) {
            const float v = acc[nt][r];
            p += v;
            q = fmaf(v, v, q);
        }
        p += __shfl_xor(p, 1);  q += __shfl_xor(q, 1);
        p += __shfl_xor(p, 2);  q += __shfl_xor(q, 2);
        p += __shfl_xor(p, 4);  q += __shfl_xor(q, 4);
        p += __shfl_xor(p, 8);  q += __shfl_xor(q, 8);
        if (col == 0) {
            const int rib = mw * 16 + quad * 4 + r;
            lsum[nw][rib] = p;
            lsq[nw][rib] = q;
        }
    }
    __syncthreads();

    #pragma unroll
    for (int r = 0; r < 4; ++r) {
        const int rib = mw * 16 + quad * 4 + r;
        const int node = row0 + rib;
        const float mu = (lsum[0][rib] + lsum[1][rib]) * (1.f / H);
        const float var = (lsq[0][rib] + lsq[1][rib]) * (1.f / H) - mu * mu;
        const float isd = rsqrtf(var + EPS);
        const float m = nmask[node];
        #pragma unroll
        for (int nt = 0; nt < 4; ++nt) {
            const float y = (fmaf(acc[nt][r] - mu, isd * gv[nt], bbv[nt])) * m;
            const unsigned short hi = f2b(y);
            const size_t a = (size_t)node * H + (nw * 4 + nt) * 16 + col;
            oxh[a] = hi;
            oxl[a] = f2b(y - b2f(hi));
        }
    }
}

// ---------------- pooling partials (xh only; 2^-9 rel error, fine) ----------------
__global__ void k_pool1(const unsigned short* __restrict__ xh,
                        const float* __restrict__ nmask, float* __restrict__ part) {
    const int b = blockIdx.x, c = blockIdx.y, h = threadIdx.x;
    const int n0 = c * PNODES;
    float s = 0.f, mx = -INFINITY, nv = 0.f;
    for (int it = 0; it < PNODES; ++it) {
        const int n = n0 + it;
        const float m = nmask[b * N + n];
        const float v = b2f(xh[((size_t)b * N + n) * H + h]) * m;
        s += v;
        if (m > 0.f) mx = fmaxf(mx, v);
        nv += m;
    }
    float* p = part + ((size_t)b * PCHUNK + c) * (2 * H + 1);
    p[h] = s;
    p[H + h] = mx;
    if (h == 0) p[2 * H] = nv;
}

// ---------------- fused pool-reduce + MLP head ----------------
__global__ __launch_bounds__(256) void k_tail(const float* __restrict__ part,
                                              const float* __restrict__ W1, const float* __restrict__ b1,
                                              const float* __restrict__ W2, const float* __restrict__ b2,
                                              float* __restrict__ out) {
    const int b = blockIdx.x, t = threadIdx.x;
    __shared__ float g[2 * H];
    __shared__ float hid[H];
    {
        float nv = 0.f;
        for (int c = 0; c < PCHUNK; ++c)
            nv += part[((size_t)b * PCHUNK + c) * (2 * H + 1) + 2 * H];
        if (t < H) {
            float s = 0.f;
            for (int c = 0; c < PCHUNK; ++c)
                s += part[((size_t)b * PCHUNK + c) * (2 * H + 1) + t];
            g[t] = s / fmaxf(nv, 1.f);
        } else {
            const int h = t - H;
            float mx = -INFINITY;
            for (int c = 0; c < PCHUNK; ++c)
                mx = fmaxf(mx, part[((size_t)b * PCHUNK + c) * (2 * H + 1) + H + h]);
            g[t] = mx;
        }
    }
    __syncthreads();
    if (t < H) {
        float a = b1[t];
        #pragma unroll 8
        for (int k = 0; k < 2 * H; ++k) a = fmaf(g[k], W1[k * H + t], a);
        hid[t] = fmaxf(a, 0.f);
    }
    __syncthreads();
    float a = b2[t];
    #pragma unroll 8
    for (int k = 0; k < H; ++k) a = fmaf(hid[k], W2[k * OUTD + t], a);
    out[(size_t)b * OUTD + t] = a;
}

extern "C" void kernel_launch(void* const* d_in, const int* in_sizes, int n_in,
                              void* d_out, int out_size, void* d_ws, size_t ws_size,
                              hipStream_t stream) {
    const float* feats = (const float*)d_in[0];
    const int*   ei    = (const int*)d_in[1];
    const float* nmask = (const float*)d_in[2];
    const float* emask = (const float*)d_in[3];
    const float* inW   = (const float*)d_in[4];
    const float* inb   = (const float*)d_in[5];
    const float* selfW = (const float*)d_in[6];
    const float* selfb = (const float*)d_in[7];
    const float* neighW= (const float*)d_in[8];
    const float* neighb= (const float*)d_in[9];
    const float* lng   = (const float*)d_in[10];
    const float* lnb   = (const float*)d_in[11];
    const float* W1    = (const float*)d_in[12];
    const float* b1    = (const float*)d_in[13];
    const float* W2    = (const float*)d_in[14];
    const float* b2    = (const float*)d_in[15];
    float* out = (float*)d_out;

    const size_t nxh = (size_t)NNODE * H;
    char* w = (char*)d_ws;
    unsigned short* xAh = (unsigned short*)w;  w += nxh * 2;
    unsigned short* xAl = (unsigned short*)w;  w += nxh * 2;
    unsigned short* xBh = (unsigned short*)w;  w += nxh * 2;
    unsigned short* xBl = (unsigned short*)w;  w += nxh * 2;
    unsigned short* Bp  = (unsigned short*)w;  w += (size_t)NLAYER * BPL * 2;
    float* part = (float*)w;                   w += (size_t)B * PCHUNK * (2 * H + 1) * 4;
    int* ecnt   = (int*)w;                     w += (size_t)NNODE * 4;
    int2* ell   = (int2*)w;                    w += (size_t)NNODE * ELLW * 8;

    k_prepB<<<NLAYER * KSTEPS * 8, 64, 0, stream>>>(selfW, neighW, Bp);
    k_inproj3<<<NNODE / TM, 256, 0, stream>>>(feats, inW, inb, xAh, xAl);

    hipMemsetAsync(ecnt, 0, (size_t)NNODE * sizeof(int), stream);
    k_fill_ell<<<B * E / 256, 256, 0, stream>>>(ei, emask, ecnt, ell);

    unsigned short* xih = xAh; unsigned short* xil = xAl;
    unsigned short* xoh = xBh; unsigned short* xol = xBl;
    for (int l = 0; l < NLAYER; ++l) {
        k_fused<<<NNODE / 32, 256, 0, stream>>>(xih, xil, ecnt, ell,
                                                Bp + (size_t)l * BPL,
                                                selfb + (size_t)l * H, neighb + (size_t)l * H,
                                                lng + (size_t)l * H, lnb + (size_t)l * H,
                                                nmask, xoh, xol);
        unsigned short* th = xih; xih = xoh; xoh = th;
        unsigned short* tl = xil; xil = xol; xol = tl;
    }

    k_pool1<<<dim3(B, PCHUNK), H, 0, stream>>>(xih, nmask, part);
    k_tail<<<B, 256, 0, stream>>>(part, W1, b1, W2, b2, out);
}

// Round 9
// 378.866 us; speedup vs baseline: 1.2303x; 1.2303x over previous
//
#include <hip/hip_runtime.h>
#include <hip/hip_bf16.h>

#define B 8
#define N 8192
#define E 65536
#define FIN 64
#define H 128
#define OUTD 256
#define NLAYER 3
#define EPS 1e-5f
#define PCHUNK 64
#define PNODES (N / PCHUNK)
#define TM 32
#define PADF 68
#define NNODE (B * N)            // 65536 rows
#define KSTEPS 16                // 4 groups x 4 k-steps of K=32
#define BPL (KSTEPS * 8 * 512)   // Bp ushort elems per layer
#define ELLW 48                  // max incoming edges/node (Poisson(8): P(>48) ~ 1e-25)

#define AS1 __attribute__((address_space(1)))
#define AS3 __attribute__((address_space(3)))

typedef float f32x4 __attribute__((ext_vector_type(4)));
typedef __bf16 bf16x8 __attribute__((ext_vector_type(8)));

__device__ __forceinline__ float b2f(unsigned short u) {
    union { float f; unsigned int i; } c; c.i = ((unsigned int)u) << 16; return c.f;
}
__device__ __forceinline__ unsigned short f2b(float f) {
    __hip_bfloat16 h = __float2bfloat16(f);          // RTNE
    return *reinterpret_cast<unsigned short*>(&h);
}

// ---------------- weight pre-pack: fragment-ordered split-bf16 B' ----------------
// groups: 0 xh*sWhi, 1 xl*sWhi, 2 xh*sWlo, 3 nh*nWhi
__global__ void k_prepB(const float* __restrict__ selfW, const float* __restrict__ neighW,
                        unsigned short* __restrict__ Bp) {
    const int idx = blockIdx.x;            // l*KSTEPS*8 + s*8 + t
    const int t = idx & 7;
    const int s = (idx >> 3) % KSTEPS;
    const int l = idx / (KSTEPS * 8);
    const int lane = threadIdx.x;
    const int quad = lane >> 4, col = lane & 15;
    const int g = s >> 2;
    const float* W = ((g < 3) ? selfW : neighW) + (size_t)l * H * H;
    const bool lo = (g == 2);
    const int n = t * 16 + col;
    unsigned short* dst = Bp + ((size_t)(l * KSTEPS + s) * 8 + t) * 512 + lane * 8;
    #pragma unroll
    for (int j = 0; j < 8; ++j) {
        const int kk = (s & 3) * 32 + quad * 8 + j;
        const float w = W[kk * H + n];
        const unsigned short hi = f2b(w);
        dst[j] = lo ? f2b(w - b2f(hi)) : hi;
    }
}

// ---------------- input projection -> split-bf16 x ----------------
__global__ __launch_bounds__(256) void k_inproj3(const float* __restrict__ feats,
                                                 const float* __restrict__ W,
                                                 const float* __restrict__ bias,
                                                 unsigned short* __restrict__ xh,
                                                 unsigned short* __restrict__ xl) {
    __shared__ float fs[TM * PADF];
    __shared__ float wB[FIN * H];
    const int tid = threadIdx.x;
    const int i = tid >> 5, j = tid & 31;
    const int row0 = blockIdx.x * TM;

    for (int v = tid; v < TM * (FIN / 4); v += 256) {
        int n = v >> 4, kq = (v & 15) << 2;
        *(float4*)&fs[n * PADF + kq] = *(const float4*)&feats[(size_t)(row0 + n) * FIN + kq];
    }
    for (int v = tid; v < FIN * H / 4; v += 256)
        *(float4*)&wB[v * 4] = *(const float4*)&W[v * 4];
    __syncthreads();

    float acc[4][4] = {};
    #pragma unroll
    for (int k4 = 0; k4 < FIN / 4; ++k4) {
        float4 xa[4];
        #pragma unroll
        for (int a = 0; a < 4; ++a)
            xa[a] = *(const float4*)&fs[(i * 4 + a) * PADF + k4 * 4];
        #pragma unroll
        for (int t = 0; t < 4; ++t) {
            float4 bs = *(const float4*)&wB[(k4 * 4 + t) * H + (j << 2)];
            #pragma unroll
            for (int a = 0; a < 4; ++a) {
                const float va = ((const float*)&xa[a])[t];
                acc[a][0] = fmaf(va, bs.x, acc[a][0]);
                acc[a][1] = fmaf(va, bs.y, acc[a][1]);
                acc[a][2] = fmaf(va, bs.z, acc[a][2]);
                acc[a][3] = fmaf(va, bs.w, acc[a][3]);
            }
        }
    }
    const float4 bv = *(const float4*)&bias[j << 2];
    #pragma unroll
    for (int a = 0; a < 4; ++a) {
        float o[4];
        o[0] = fmaxf(acc[a][0] + bv.x, 0.f);
        o[1] = fmaxf(acc[a][1] + bv.y, 0.f);
        o[2] = fmaxf(acc[a][2] + bv.z, 0.f);
        o[3] = fmaxf(acc[a][3] + bv.w, 0.f);
        ushort4 h4, l4;
        h4.x = f2b(o[0]); l4.x = f2b(o[0] - b2f(h4.x));
        h4.y = f2b(o[1]); l4.y = f2b(o[1] - b2f(h4.y));
        h4.z = f2b(o[2]); l4.z = f2b(o[2] - b2f(h4.z));
        h4.w = f2b(o[3]); l4.w = f2b(o[3] - b2f(h4.w));
        const size_t a0 = (size_t)(row0 + i * 4 + a) * H + (j << 2);
        *(ushort4*)&xh[a0] = h4;
        *(ushort4*)&xl[a0] = l4;
    }
}

// ---------------- ELL build: one fill pass (ecnt pre-zeroed) ----------------
__global__ void k_fill_ell(const int* __restrict__ ei, const float* __restrict__ emask,
                           int* __restrict__ ecnt, int2* __restrict__ ell) {
    const int ge = blockIdx.x * 256 + threadIdx.x;       // b*E + e
    const float m = emask[ge];
    if (m > 0.f) {
        const int b = ge >> 16, e = ge & 0xFFFF;
        const int tgt = ei[(b * 2 + 1) * E + e];
        const int src = ei[(b * 2) * E + e];
        const int r = b * N + tgt;
        const int p = atomicAdd(&ecnt[r], 1);
        if (p < ELLW) {
            int2 v; v.x = b * N + src; v.y = __float_as_int(m);
            ell[(size_t)r * ELLW + p] = v;
        }
    }
}

// ---------------- gather from ELL: one wave per row, batch<->XCD pinned ----------------
__global__ __launch_bounds__(256) void k_gather4(const unsigned int* __restrict__ xh32,
                                                 const int* __restrict__ ecnt,
                                                 const int2* __restrict__ ell,
                                                 unsigned int* __restrict__ nh32) {
    const int beta = blockIdx.x;               // 0..16383
    const int b = beta & 7;
    const int grp = beta >> 3;                 // 0..2047
    const int wave = threadIdx.x >> 6, lane = threadIdx.x & 63;
    const int r = b * N + grp * 4 + wave;
    const int cnt = min(ecnt[r], ELLW);
    int sv = 0; float mv = 0.f;
    if (lane < cnt) {
        const int2 ev = ell[(size_t)r * ELLW + lane];
        sv = ev.x; mv = __int_as_float(ev.y);
    }
    float a0 = 0.f, a1 = 0.f, c = 0.f;
    for (int jj = 0; jj < cnt; ++jj) {
        const int src = __shfl(sv, jj);
        const float m = __shfl(mv, jj);
        const unsigned int u = xh32[(size_t)src * 64 + lane];
        union { unsigned int i; float f; } lo, hi;
        lo.i = u << 16;
        hi.i = u & 0xFFFF0000u;
        a0 = fmaf(lo.f, m, a0);
        a1 = fmaf(hi.f, m, a1);
        c += m;
    }
    const float inv = 1.f / fmaxf(c, 1.f);
    nh32[(size_t)r * 64 + lane] = (unsigned int)f2b(a0 * inv) | ((unsigned int)f2b(a1 * inv) << 16);
}

// ---------------- fused layer v6: LDS-staged B (global_load_lds), 64 rows/block ----------------
// 1024 blocks x 4 waves. wave w: mg=w>>1 (m-tiles mg*2,mg*2+1), nw=w&1 (n-tiles nw*4..+3).
// K-loop: 8 chunks of 2 steps; B chunk (16 KB) double-buffered in LDS via global_load_lds(16B);
// A (xh/xl/nh) register-prefetched one chunk ahead. In-place: block touches only its 64 rows.
__global__ __launch_bounds__(256) void k_layer6(const unsigned short* __restrict__ xinh,
                                                const unsigned short* __restrict__ xinl,
                                                const unsigned short* __restrict__ nh,
                                                const unsigned short* __restrict__ Bp,
                                                const float* __restrict__ sb,
                                                const float* __restrict__ nb,
                                                const float* __restrict__ lng,
                                                const float* __restrict__ lnb,
                                                const float* __restrict__ nmask,
                                                unsigned short* __restrict__ oxh,
                                                unsigned short* __restrict__ oxl) {
    __shared__ __align__(16) unsigned short bbuf[2][16 * 512];   // 2 x 16 KB
    __shared__ float lsum[2][64];
    __shared__ float lsq[2][64];

    const int tid = threadIdx.x;
    const int wv = tid >> 6, lane = tid & 63;
    const int quad = lane >> 4, col = lane & 15;
    const int mg = wv >> 1, nw = wv & 1;
    const int u = blockIdx.x;
    const int b = u & 7;
    const int row0 = b * N + (u >> 3) * 64;       // batch-pinned to XCD b

    size_t abase[2];
    #pragma unroll
    for (int mt = 0; mt < 2; ++mt)
        abase[mt] = (size_t)(row0 + (mg * 2 + mt) * 16 + col) * H + quad * 8;

    // stage chunk 0 B (tiles 0..15; wave wv stages tiles wv*4..+3)
    #pragma unroll
    for (int i = 0; i < 4; ++i) {
        const unsigned short* g = Bp + (size_t)(wv * 4 + i) * 512 + lane * 8;
        __builtin_amdgcn_global_load_lds((const AS1 unsigned int*)g,
                                         (AS3 unsigned int*)&bbuf[0][(wv * 4 + i) * 512],
                                         16, 0, 0);
    }
    // prefetch A chunk 0 (group 0 = xh; steps 0,1 -> ko 0,32)
    bf16x8 aC[2][2];
    #pragma unroll
    for (int j = 0; j < 2; ++j)
        #pragma unroll
        for (int mt = 0; mt < 2; ++mt)
            aC[j][mt] = *(const bf16x8*)&xinh[abase[mt] + j * 32];

    f32x4 acc[2][4] = {};

    #pragma unroll
    for (int c = 0; c < 8; ++c) {
        __syncthreads();                     // chunk c staged; buf[(c+1)&1] free
        bf16x8 aN[2][2];
        if (c < 7) {
            const int c1 = c + 1;
            #pragma unroll
            for (int i = 0; i < 4; ++i) {
                const unsigned short* g = Bp + (size_t)(c1 * 16 + wv * 4 + i) * 512 + lane * 8;
                __builtin_amdgcn_global_load_lds((const AS1 unsigned int*)g,
                                                 (AS3 unsigned int*)&bbuf[c1 & 1][(wv * 4 + i) * 512],
                                                 16, 0, 0);
            }
            const int g1 = c1 >> 1;
            const unsigned short* A1 = (g1 == 1) ? xinl : (g1 == 3) ? nh : xinh;
            #pragma unroll
            for (int j = 0; j < 2; ++j)
                #pragma unroll
                for (int mt = 0; mt < 2; ++mt)
                    aN[j][mt] = *(const bf16x8*)&A1[abase[mt] + ((c1 & 1) * 2 + j) * 32];
        }
        #pragma unroll
        for (int j = 0; j < 2; ++j) {
            bf16x8 bf[4];
            #pragma unroll
            for (int nt = 0; nt < 4; ++nt)
                bf[nt] = *(const bf16x8*)&bbuf[c & 1][(j * 8 + nw * 4 + nt) * 512 + lane * 8];
            #pragma unroll
            for (int mt = 0; mt < 2; ++mt)
                #pragma unroll
                for (int nt = 0; nt < 4; ++nt)
                    acc[mt][nt] = __builtin_amdgcn_mfma_f32_16x16x32_bf16(aC[j][mt], bf[nt], acc[mt][nt], 0, 0, 0);
        }
        #pragma unroll
        for (int j = 0; j < 2; ++j)
            #pragma unroll
            for (int mt = 0; mt < 2; ++mt)
                aC[j][mt] = aN[j][mt];
    }

    // bias + relu (C/D: row = quad*4 + r, col = lane&15; h = (nw*4+nt)*16 + col)
    float sbv[4], nbv[4], gv[4], bbv[4];
    #pragma unroll
    for (int nt = 0; nt < 4; ++nt) {
        const int hh = (nw * 4 + nt) * 16 + col;
        sbv[nt] = sb[hh]; nbv[nt] = nb[hh]; gv[nt] = lng[hh]; bbv[nt] = lnb[hh];
    }
    #pragma unroll
    for (int mt = 0; mt < 2; ++mt)
        #pragma unroll
        for (int nt = 0; nt < 4; ++nt)
            #pragma unroll
            for (int r = 0; r < 4; ++r)
                acc[mt][nt][r] = fmaxf(acc[mt][nt][r] + sbv[nt] + nbv[nt], 0.f);

    // LN partials: wave covers 64 of 128 h for its 32 rows
    #pragma unroll
    for (int mt = 0; mt < 2; ++mt)
        #pragma unroll
        for (int r = 0; r < 4; ++r) {
            float p = 0.f, q = 0.f;
            #pragma unroll
            for (int nt = 0; nt < 4; ++nt) {
                const float v = acc[mt][nt][r];
                p += v;
                q = fmaf(v, v, q);
            }
            p += __shfl_xor(p, 1);  q += __shfl_xor(q, 1);
            p += __shfl_xor(p, 2);  q += __shfl_xor(q, 2);
            p += __shfl_xor(p, 4);  q += __shfl_xor(q, 4);
            p += __shfl_xor(p, 8);  q += __shfl_xor(q, 8);
            if (col == 0) {
                const int rib = (mg * 2 + mt) * 16 + quad * 4 + r;
                lsum[nw][rib] = p;
                lsq[nw][rib] = q;
            }
        }
    __syncthreads();

    #pragma unroll
    for (int mt = 0; mt < 2; ++mt)
        #pragma unroll
        for (int r = 0; r < 4; ++r) {
            const int rib = (mg * 2 + mt) * 16 + quad * 4 + r;
            const int node = row0 + rib;
            const float mu = (lsum[0][rib] + lsum[1][rib]) * (1.f / H);
            const float var = (lsq[0][rib] + lsq[1][rib]) * (1.f / H) - mu * mu;
            const float isd = rsqrtf(var + EPS);
            const float m = nmask[node];
            #pragma unroll
            for (int nt = 0; nt < 4; ++nt) {
                const float y = (fmaf(acc[mt][nt][r] - mu, isd * gv[nt], bbv[nt])) * m;
                const unsigned short hi = f2b(y);
                const size_t a = (size_t)node * H + (nw * 4 + nt) * 16 + col;
                oxh[a] = hi;
                oxl[a] = f2b(y - b2f(hi));
            }
        }
}

// ---------------- pooling partials (xh only; 2^-9 rel error, fine) ----------------
__global__ void k_pool1(const unsigned short* __restrict__ xh,
                        const float* __restrict__ nmask, float* __restrict__ part) {
    const int b = blockIdx.x, c = blockIdx.y, h = threadIdx.x;
    const int n0 = c * PNODES;
    float s = 0.f, mx = -INFINITY, nv = 0.f;
    for (int it = 0; it < PNODES; ++it) {
        const int n = n0 + it;
        const float m = nmask[b * N + n];
        const float v = b2f(xh[((size_t)b * N + n) * H + h]) * m;
        s += v;
        if (m > 0.f) mx = fmaxf(mx, v);
        nv += m;
    }
    float* p = part + ((size_t)b * PCHUNK + c) * (2 * H + 1);
    p[h] = s;
    p[H + h] = mx;
    if (h == 0) p[2 * H] = nv;
}

// ---------------- fused pool-reduce + MLP head ----------------
__global__ __launch_bounds__(256) void k_tail(const float* __restrict__ part,
                                              const float* __restrict__ W1, const float* __restrict__ b1,
                                              const float* __restrict__ W2, const float* __restrict__ b2,
                                              float* __restrict__ out) {
    const int b = blockIdx.x, t = threadIdx.x;
    __shared__ float g[2 * H];
    __shared__ float hid[H];
    {
        float nv = 0.f;
        for (int c = 0; c < PCHUNK; ++c)
            nv += part[((size_t)b * PCHUNK + c) * (2 * H + 1) + 2 * H];
        if (t < H) {
            float s = 0.f;
            for (int c = 0; c < PCHUNK; ++c)
                s += part[((size_t)b * PCHUNK + c) * (2 * H + 1) + t];
            g[t] = s / fmaxf(nv, 1.f);
        } else {
            const int h = t - H;
            float mx = -INFINITY;
            for (int c = 0; c < PCHUNK; ++c)
                mx = fmaxf(mx, part[((size_t)b * PCHUNK + c) * (2 * H + 1) + H + h]);
            g[t] = mx;
        }
    }
    __syncthreads();
    if (t < H) {
        float a = b1[t];
        #pragma unroll 8
        for (int k = 0; k < 2 * H; ++k) a = fmaf(g[k], W1[k * H + t], a);
        hid[t] = fmaxf(a, 0.f);
    }
    __syncthreads();
    float a = b2[t];
    #pragma unroll 8
    for (int k = 0; k < H; ++k) a = fmaf(hid[k], W2[k * OUTD + t], a);
    out[(size_t)b * OUTD + t] = a;
}

extern "C" void kernel_launch(void* const* d_in, const int* in_sizes, int n_in,
                              void* d_out, int out_size, void* d_ws, size_t ws_size,
                              hipStream_t stream) {
    const float* feats = (const float*)d_in[0];
    const int*   ei    = (const int*)d_in[1];
    const float* nmask = (const float*)d_in[2];
    const float* emask = (const float*)d_in[3];
    const float* inW   = (const float*)d_in[4];
    const float* inb   = (const float*)d_in[5];
    const float* selfW = (const float*)d_in[6];
    const float* selfb = (const float*)d_in[7];
    const float* neighW= (const float*)d_in[8];
    const float* neighb= (const float*)d_in[9];
    const float* lng   = (const float*)d_in[10];
    const float* lnb   = (const float*)d_in[11];
    const float* W1    = (const float*)d_in[12];
    const float* b1    = (const float*)d_in[13];
    const float* W2    = (const float*)d_in[14];
    const float* b2    = (const float*)d_in[15];
    float* out = (float*)d_out;

    const size_t nxh = (size_t)NNODE * H;
    char* w = (char*)d_ws;
    unsigned short* xh  = (unsigned short*)w;  w += nxh * 2;
    unsigned short* xl  = (unsigned short*)w;  w += nxh * 2;
    unsigned short* nh  = (unsigned short*)w;  w += nxh * 2;
    unsigned short* Bp  = (unsigned short*)w;  w += (size_t)NLAYER * BPL * 2;
    float* part = (float*)w;                   w += (size_t)B * PCHUNK * (2 * H + 1) * 4;
    int* ecnt   = (int*)w;                     w += (size_t)NNODE * 4;
    int2* ell   = (int2*)w;                    w += (size_t)NNODE * ELLW * 8;

    k_prepB<<<NLAYER * KSTEPS * 8, 64, 0, stream>>>(selfW, neighW, Bp);
    k_inproj3<<<NNODE / TM, 256, 0, stream>>>(feats, inW, inb, xh, xl);

    hipMemsetAsync(ecnt, 0, (size_t)NNODE * sizeof(int), stream);
    k_fill_ell<<<B * E / 256, 256, 0, stream>>>(ei, emask, ecnt, ell);

    for (int l = 0; l < NLAYER; ++l) {
        k_gather4<<<NNODE / 4, 256, 0, stream>>>((const unsigned int*)xh, ecnt, ell,
                                                 (unsigned int*)nh);
        k_layer6<<<NNODE / 64, 256, 0, stream>>>(xh, xl, nh,
                                                 Bp + (size_t)l * BPL,
                                                 selfb + (size_t)l * H, neighb + (size_t)l * H,
                                                 lng + (size_t)l * H, lnb + (size_t)l * H,
                                                 nmask, xh, xl);
    }

    k_pool1<<<dim3(B, PCHUNK), H, 0, stream>>>(xh, nmask, part);
    k_tail<<<B, 256, 0, stream>>>(part, W1, b1, W2, b2, out);
}

// Round 10
// 325.850 us; speedup vs baseline: 1.4304x; 1.1627x over previous
//
#include <hip/hip_runtime.h>
#include <hip/hip_bf16.h>

#define B 8
#define N 8192
#define E 65536
#define FIN 64
#define H 128
#define OUTD 256
#define NLAYER 3
#define EPS 1e-5f
#define PCHUNK 64
#define PNODES (N / PCHUNK)
#define NNODE (B * N)            // 65536 rows
#define KSTEPS 12                // 3 groups x 4 k-steps of K=32 (xh*sWhi, xl*sWhi, nh*nWhi)
#define BPL (KSTEPS * 8 * 512)   // Bp ushort elems per layer
#define INSTEPS 6                // inproj: 3 groups x 2 k-steps (fh*Whi, fl*Whi, fh*Wlo)
#define ELLW 48                  // max incoming edges/node (Poisson(8): P(>48) ~ 1e-25)

#define AS1 __attribute__((address_space(1)))
#define AS3 __attribute__((address_space(3)))

typedef float f32x4 __attribute__((ext_vector_type(4)));
typedef __bf16 bf16x8 __attribute__((ext_vector_type(8)));

__device__ __forceinline__ float b2f(unsigned short u) {
    union { float f; unsigned int i; } c; c.i = ((unsigned int)u) << 16; return c.f;
}
__device__ __forceinline__ unsigned short f2b(float f) {
    __hip_bfloat16 h = __float2bfloat16(f);          // RTNE
    return *reinterpret_cast<unsigned short*>(&h);
}

// ---------------- unified weight pre-pack (layers + inproj) ----------------
// Layer groups (hi only): 0 xh*sWhi, 1 xl*sWhi, 2 nh*nWhi
// Inproj groups: 0 fh*Whi, 1 fl*Whi, 2 fh*Wlo
__global__ void k_prep(const float* __restrict__ selfW, const float* __restrict__ neighW,
                       const float* __restrict__ inW,
                       unsigned short* __restrict__ Bp, unsigned short* __restrict__ Bpi) {
    const int idx = blockIdx.x;
    const int lane = threadIdx.x;
    const int quad = lane >> 4, col = lane & 15;
    if (idx < NLAYER * KSTEPS * 8) {
        const int t = idx & 7;
        const int s = (idx >> 3) % KSTEPS;
        const int l = idx / (KSTEPS * 8);
        const int g = s >> 2;
        const float* W = ((g < 2) ? selfW : neighW) + (size_t)l * H * H;
        const int n = t * 16 + col;
        unsigned short* dst = Bp + ((size_t)(l * KSTEPS + s) * 8 + t) * 512 + lane * 8;
        #pragma unroll
        for (int j = 0; j < 8; ++j) {
            const int kk = (s & 3) * 32 + quad * 8 + j;
            dst[j] = f2b(W[kk * H + n]);
        }
    } else {
        const int idx2 = idx - NLAYER * KSTEPS * 8;
        const int t = idx2 & 7;
        const int s = idx2 >> 3;                     // 0..5
        const int g = s >> 1;
        const bool lo = (g == 2);
        const int n = t * 16 + col;
        unsigned short* dst = Bpi + ((size_t)(s * 8 + t)) * 512 + lane * 8;
        #pragma unroll
        for (int j = 0; j < 8; ++j) {
            const int kk = (s & 1) * 32 + quad * 8 + j;   // K = 64
            const float w = inW[kk * H + n];
            const unsigned short hi = f2b(w);
            dst[j] = lo ? f2b(w - b2f(hi)) : hi;
        }
    }
}

// ---------------- input projection via MFMA: x = relu(feats @ inW + b) -> split-bf16 ----------------
// 1024 blocks x 4 waves; wave (mg,nw): m-tiles mg*2..+1, n-tiles nw*4..+3.
// A: 8 consecutive f32 feats per lane, split hi/lo in regs (exact to 2^-16).
__global__ __launch_bounds__(256) void k_inproj4(const float* __restrict__ feats,
                                                 const unsigned short* __restrict__ Bpi,
                                                 const float* __restrict__ bias,
                                                 unsigned short* __restrict__ xh,
                                                 unsigned short* __restrict__ xl) {
    const int tid = threadIdx.x;
    const int wv = tid >> 6, lane = tid & 63;
    const int quad = lane >> 4, col = lane & 15;
    const int mg = wv >> 1, nw = wv & 1;
    const int row0 = blockIdx.x * 64;

    bf16x8 fh[2][2], fl[2][2];
    #pragma unroll
    for (int mt = 0; mt < 2; ++mt) {
        const int row = row0 + (mg * 2 + mt) * 16 + col;
        #pragma unroll
        for (int j = 0; j < 2; ++j) {
            const float* src = &feats[(size_t)row * FIN + j * 32 + quad * 8];
            const float4 v0 = *(const float4*)src;
            const float4 v1 = *(const float4*)(src + 4);
            const float fv[8] = {v0.x, v0.y, v0.z, v0.w, v1.x, v1.y, v1.z, v1.w};
            union { bf16x8 v; unsigned short u[8]; } Hh, Ll;
            #pragma unroll
            for (int q = 0; q < 8; ++q) {
                const unsigned short hu = f2b(fv[q]);
                Hh.u[q] = hu;
                Ll.u[q] = f2b(fv[q] - b2f(hu));
            }
            fh[mt][j] = Hh.v;
            fl[mt][j] = Ll.v;
        }
    }

    f32x4 acc[2][4] = {};
    bf16x8 bC[4];
    #pragma unroll
    for (int nt = 0; nt < 4; ++nt)
        bC[nt] = *(const bf16x8*)&Bpi[((size_t)(nw * 4 + nt)) * 512 + lane * 8];

    #pragma unroll
    for (int s = 0; s < INSTEPS; ++s) {
        bf16x8 bN[4];
        if (s + 1 < INSTEPS) {
            #pragma unroll
            for (int nt = 0; nt < 4; ++nt)
                bN[nt] = *(const bf16x8*)&Bpi[((size_t)(s + 1) * 8 + nw * 4 + nt) * 512 + lane * 8];
        }
        const int g = s >> 1, j = s & 1;
        #pragma unroll
        for (int mt = 0; mt < 2; ++mt) {
            const bf16x8 a = (g == 1) ? fl[mt][j] : fh[mt][j];
            #pragma unroll
            for (int nt = 0; nt < 4; ++nt)
                acc[mt][nt] = __builtin_amdgcn_mfma_f32_16x16x32_bf16(a, bC[nt], acc[mt][nt], 0, 0, 0);
        }
        #pragma unroll
        for (int nt = 0; nt < 4; ++nt) bC[nt] = bN[nt];
    }

    #pragma unroll
    for (int nt = 0; nt < 4; ++nt) {
        const int hh = (nw * 4 + nt) * 16 + col;
        const float bv = bias[hh];
        #pragma unroll
        for (int mt = 0; mt < 2; ++mt)
            #pragma unroll
            for (int r = 0; r < 4; ++r) {
                const int row = row0 + (mg * 2 + mt) * 16 + quad * 4 + r;
                const float y = fmaxf(acc[mt][nt][r] + bv, 0.f);
                const unsigned short hi = f2b(y);
                const size_t a = (size_t)row * H + hh;
                xh[a] = hi;
                xl[a] = f2b(y - b2f(hi));
            }
    }
}

// ---------------- ELL build: one fill pass (ecnt pre-zeroed) ----------------
__global__ void k_fill_ell(const int* __restrict__ ei, const float* __restrict__ emask,
                           int* __restrict__ ecnt, int2* __restrict__ ell) {
    const int ge = blockIdx.x * 256 + threadIdx.x;       // b*E + e
    const float m = emask[ge];
    if (m > 0.f) {
        const int b = ge >> 16, e = ge & 0xFFFF;
        const int tgt = ei[(b * 2 + 1) * E + e];
        const int src = ei[(b * 2) * E + e];
        const int r = b * N + tgt;
        const int p = atomicAdd(&ecnt[r], 1);
        if (p < ELLW) {
            int2 v; v.x = b * N + src; v.y = __float_as_int(m);
            ell[(size_t)r * ELLW + p] = v;
        }
    }
}

// ---------------- gather from ELL: one wave per row, unroll-4 predicated ----------------
__global__ __launch_bounds__(256) void k_gather5(const unsigned int* __restrict__ xh32,
                                                 const int* __restrict__ ecnt,
                                                 const int2* __restrict__ ell,
                                                 unsigned int* __restrict__ nh32) {
    const int beta = blockIdx.x;               // 0..16383
    const int b = beta & 7;
    const int grp = beta >> 3;                 // 0..2047
    const int wave = threadIdx.x >> 6, lane = threadIdx.x & 63;
    const int r = b * N + grp * 4 + wave;
    const int cnt = min(ecnt[r], ELLW);
    int sv = 0; float mv = 0.f;
    if (lane < cnt) {
        const int2 ev = ell[(size_t)r * ELLW + lane];
        sv = ev.x; mv = __int_as_float(ev.y);
    }
    float a0 = 0.f, a1 = 0.f, c = 0.f;
    const int cnt4 = (cnt + 3) & ~3;
    for (int jj = 0; jj < cnt4; jj += 4) {
        #pragma unroll
        for (int q = 0; q < 4; ++q) {
            const int src = __shfl(sv, jj + q);      // lanes >= cnt give sv=0, mv=0
            const float m = __shfl(mv, jj + q);
            const unsigned int u = xh32[(size_t)src * 64 + lane];
            union { unsigned int i; float f; } lo, hi;
            lo.i = u << 16;
            hi.i = u & 0xFFFF0000u;
            a0 = fmaf(lo.f, m, a0);
            a1 = fmaf(hi.f, m, a1);
            c += m;
        }
    }
    const float inv = 1.f / fmaxf(c, 1.f);
    nh32[(size_t)r * 64 + lane] = (unsigned int)f2b(a0 * inv) | ((unsigned int)f2b(a1 * inv) << 16);
}

// ---------------- fused layer v7: LDS-staged B, KSTEPS=12, 6 chunks ----------------
// 1024 blocks x 4 waves. wave w: mg=w>>1 (m-tiles mg*2,mg*2+1), nw=w&1 (n-tiles nw*4..+3).
// chunk c (2 k-steps, 16 KB B) double-buffered via global_load_lds(16B); A register-prefetched.
// In-place: block touches only its 64 rows.
__global__ __launch_bounds__(256) void k_layer7(const unsigned short* __restrict__ xinh,
                                                const unsigned short* __restrict__ xinl,
                                                const unsigned short* __restrict__ nh,
                                                const unsigned short* __restrict__ Bp,
                                                const float* __restrict__ sb,
                                                const float* __restrict__ nb,
                                                const float* __restrict__ lng,
                                                const float* __restrict__ lnb,
                                                const float* __restrict__ nmask,
                                                unsigned short* __restrict__ oxh,
                                                unsigned short* __restrict__ oxl) {
    __shared__ __align__(16) unsigned short bbuf[2][16 * 512];   // 2 x 16 KB
    __shared__ float lsum[2][64];
    __shared__ float lsq[2][64];

    const int tid = threadIdx.x;
    const int wv = tid >> 6, lane = tid & 63;
    const int quad = lane >> 4, col = lane & 15;
    const int mg = wv >> 1, nw = wv & 1;
    const int u = blockIdx.x;
    const int b = u & 7;
    const int row0 = b * N + (u >> 3) * 64;       // batch-pinned to XCD b

    size_t abase[2];
    #pragma unroll
    for (int mt = 0; mt < 2; ++mt)
        abase[mt] = (size_t)(row0 + (mg * 2 + mt) * 16 + col) * H + quad * 8;

    // stage chunk 0 B (tiles 0..15; wave wv stages tiles wv*4..+3)
    #pragma unroll
    for (int i = 0; i < 4; ++i) {
        const unsigned short* g = Bp + (size_t)(wv * 4 + i) * 512 + lane * 8;
        __builtin_amdgcn_global_load_lds((const AS1 unsigned int*)g,
                                         (AS3 unsigned int*)&bbuf[0][(wv * 4 + i) * 512],
                                         16, 0, 0);
    }
    // prefetch A chunk 0 (group 0 = xh; steps 0,1 -> ko 0,32)
    bf16x8 aC[2][2];
    #pragma unroll
    for (int j = 0; j < 2; ++j)
        #pragma unroll
        for (int mt = 0; mt < 2; ++mt)
            aC[j][mt] = *(const bf16x8*)&xinh[abase[mt] + j * 32];

    f32x4 acc[2][4] = {};

    #pragma unroll
    for (int c = 0; c < 6; ++c) {
        __syncthreads();                     // chunk c staged; buf[(c+1)&1] free
        bf16x8 aN[2][2];
        if (c < 5) {
            const int c1 = c + 1;
            #pragma unroll
            for (int i = 0; i < 4; ++i) {
                const unsigned short* g = Bp + (size_t)(c1 * 16 + wv * 4 + i) * 512 + lane * 8;
                __builtin_amdgcn_global_load_lds((const AS1 unsigned int*)g,
                                                 (AS3 unsigned int*)&bbuf[c1 & 1][(wv * 4 + i) * 512],
                                                 16, 0, 0);
            }
            const int g1 = c1 >> 1;          // 0: xh, 1: xl, 2: nh
            const unsigned short* A1 = (g1 == 1) ? xinl : (g1 == 2) ? nh : xinh;
            #pragma unroll
            for (int j = 0; j < 2; ++j)
                #pragma unroll
                for (int mt = 0; mt < 2; ++mt)
                    aN[j][mt] = *(const bf16x8*)&A1[abase[mt] + ((c1 & 1) * 2 + j) * 32];
        }
        #pragma unroll
        for (int j = 0; j < 2; ++j) {
            bf16x8 bf[4];
            #pragma unroll
            for (int nt = 0; nt < 4; ++nt)
                bf[nt] = *(const bf16x8*)&bbuf[c & 1][(j * 8 + nw * 4 + nt) * 512 + lane * 8];
            #pragma unroll
            for (int mt = 0; mt < 2; ++mt)
                #pragma unroll
                for (int nt = 0; nt < 4; ++nt)
                    acc[mt][nt] = __builtin_amdgcn_mfma_f32_16x16x32_bf16(aC[j][mt], bf[nt], acc[mt][nt], 0, 0, 0);
        }
        #pragma unroll
        for (int j = 0; j < 2; ++j)
            #pragma unroll
            for (int mt = 0; mt < 2; ++mt)
                aC[j][mt] = aN[j][mt];
    }

    // bias + relu (C/D: row = quad*4 + r, col = lane&15; h = (nw*4+nt)*16 + col)
    float sbv[4], nbv[4], gv[4], bbv[4];
    #pragma unroll
    for (int nt = 0; nt < 4; ++nt) {
        const int hh = (nw * 4 + nt) * 16 + col;
        sbv[nt] = sb[hh]; nbv[nt] = nb[hh]; gv[nt] = lng[hh]; bbv[nt] = lnb[hh];
    }
    #pragma unroll
    for (int mt = 0; mt < 2; ++mt)
        #pragma unroll
        for (int nt = 0; nt < 4; ++nt)
            #pragma unroll
            for (int r = 0; r < 4; ++r)
                acc[mt][nt][r] = fmaxf(acc[mt][nt][r] + sbv[nt] + nbv[nt], 0.f);

    // LN partials: wave covers 64 of 128 h for its 32 rows
    #pragma unroll
    for (int mt = 0; mt < 2; ++mt)
        #pragma unroll
        for (int r = 0; r < 4; ++r) {
            float p = 0.f, q = 0.f;
            #pragma unroll
            for (int nt = 0; nt < 4; ++nt) {
                const float v = acc[mt][nt][r];
                p += v;
                q = fmaf(v, v, q);
            }
            p += __shfl_xor(p, 1);  q += __shfl_xor(q, 1);
            p += __shfl_xor(p, 2);  q += __shfl_xor(q, 2);
            p += __shfl_xor(p, 4);  q += __shfl_xor(q, 4);
            p += __shfl_xor(p, 8);  q += __shfl_xor(q, 8);
            if (col == 0) {
                const int rib = (mg * 2 + mt) * 16 + quad * 4 + r;
                lsum[nw][rib] = p;
                lsq[nw][rib] = q;
            }
        }
    __syncthreads();

    #pragma unroll
    for (int mt = 0; mt < 2; ++mt)
        #pragma unroll
        for (int r = 0; r < 4; ++r) {
            const int rib = (mg * 2 + mt) * 16 + quad * 4 + r;
            const int node = row0 + rib;
            const float mu = (lsum[0][rib] + lsum[1][rib]) * (1.f / H);
            const float var = (lsq[0][rib] + lsq[1][rib]) * (1.f / H) - mu * mu;
            const float isd = rsqrtf(var + EPS);
            const float m = nmask[node];
            #pragma unroll
            for (int nt = 0; nt < 4; ++nt) {
                const float y = (fmaf(acc[mt][nt][r] - mu, isd * gv[nt], bbv[nt])) * m;
                const unsigned short hi = f2b(y);
                const size_t a = (size_t)node * H + (nw * 4 + nt) * 16 + col;
                oxh[a] = hi;
                oxl[a] = f2b(y - b2f(hi));
            }
        }
}

// ---------------- pooling partials (xh only; 2^-9 rel error, fine) ----------------
__global__ void k_pool1(const unsigned short* __restrict__ xh,
                        const float* __restrict__ nmask, float* __restrict__ part) {
    const int b = blockIdx.x, c = blockIdx.y, h = threadIdx.x;
    const int n0 = c * PNODES;
    float s = 0.f, mx = -INFINITY, nv = 0.f;
    for (int it = 0; it < PNODES; ++it) {
        const int n = n0 + it;
        const float m = nmask[b * N + n];
        const float v = b2f(xh[((size_t)b * N + n) * H + h]) * m;
        s += v;
        if (m > 0.f) mx = fmaxf(mx, v);
        nv += m;
    }
    float* p = part + ((size_t)b * PCHUNK + c) * (2 * H + 1);
    p[h] = s;
    p[H + h] = mx;
    if (h == 0) p[2 * H] = nv;
}

// ---------------- fused pool-reduce + MLP head ----------------
__global__ __launch_bounds__(256) void k_tail(const float* __restrict__ part,
                                              const float* __restrict__ W1, const float* __restrict__ b1,
                                              const float* __restrict__ W2, const float* __restrict__ b2,
                                              float* __restrict__ out) {
    const int b = blockIdx.x, t = threadIdx.x;
    __shared__ float g[2 * H];
    __shared__ float hid[H];
    {
        float nv = 0.f;
        for (int c = 0; c < PCHUNK; ++c)
            nv += part[((size_t)b * PCHUNK + c) * (2 * H + 1) + 2 * H];
        if (t < H) {
            float s = 0.f;
            for (int c = 0; c < PCHUNK; ++c)
                s += part[((size_t)b * PCHUNK + c) * (2 * H + 1) + t];
            g[t] = s / fmaxf(nv, 1.f);
        } else {
            const int h = t - H;
            float mx = -INFINITY;
            for (int c = 0; c < PCHUNK; ++c)
                mx = fmaxf(mx, part[((size_t)b * PCHUNK + c) * (2 * H + 1) + H + h]);
            g[t] = mx;
        }
    }
    __syncthreads();
    if (t < H) {
        float a = b1[t];
        #pragma unroll 8
        for (int k = 0; k < 2 * H; ++k) a = fmaf(g[k], W1[k * H + t], a);
        hid[t] = fmaxf(a, 0.f);
    }
    __syncthreads();
    float a = b2[t];
    #pragma unroll 8
    for (int k = 0; k < H; ++k) a = fmaf(hid[k], W2[k * OUTD + t], a);
    out[(size_t)b * OUTD + t] = a;
}

extern "C" void kernel_launch(void* const* d_in, const int* in_sizes, int n_in,
                              void* d_out, int out_size, void* d_ws, size_t ws_size,
                              hipStream_t stream) {
    const float* feats = (const float*)d_in[0];
    const int*   ei    = (const int*)d_in[1];
    const float* nmask = (const float*)d_in[2];
    const float* emask = (const float*)d_in[3];
    const float* inW   = (const float*)d_in[4];
    const float* inb   = (const float*)d_in[5];
    const float* selfW = (const float*)d_in[6];
    const float* selfb = (const float*)d_in[7];
    const float* neighW= (const float*)d_in[8];
    const float* neighb= (const float*)d_in[9];
    const float* lng   = (const float*)d_in[10];
    const float* lnb   = (const float*)d_in[11];
    const float* W1    = (const float*)d_in[12];
    const float* b1    = (const float*)d_in[13];
    const float* W2    = (const float*)d_in[14];
    const float* b2    = (const float*)d_in[15];
    float* out = (float*)d_out;

    const size_t nxh = (size_t)NNODE * H;
    char* w = (char*)d_ws;
    unsigned short* xh  = (unsigned short*)w;  w += nxh * 2;
    unsigned short* xl  = (unsigned short*)w;  w += nxh * 2;
    unsigned short* nh  = (unsigned short*)w;  w += nxh * 2;
    unsigned short* Bp  = (unsigned short*)w;  w += (size_t)NLAYER * BPL * 2;
    unsigned short* Bpi = (unsigned short*)w;  w += (size_t)INSTEPS * 8 * 512 * 2;
    float* part = (float*)w;                   w += (size_t)B * PCHUNK * (2 * H + 1) * 4;
    int* ecnt   = (int*)w;                     w += (size_t)NNODE * 4;
    int2* ell   = (int2*)w;                    w += (size_t)NNODE * ELLW * 8;

    k_prep<<<NLAYER * KSTEPS * 8 + INSTEPS * 8, 64, 0, stream>>>(selfW, neighW, inW, Bp, Bpi);
    k_inproj4<<<NNODE / 64, 256, 0, stream>>>(feats, Bpi, inb, xh, xl);

    hipMemsetAsync(ecnt, 0, (size_t)NNODE * sizeof(int), stream);
    k_fill_ell<<<B * E / 256, 256, 0, stream>>>(ei, emask, ecnt, ell);

    for (int l = 0; l < NLAYER; ++l) {
        k_gather5<<<NNODE / 4, 256, 0, stream>>>((const unsigned int*)xh, ecnt, ell,
                                                 (unsigned int*)nh);
        k_layer7<<<NNODE / 64, 256, 0, stream>>>(xh, xl, nh,
                                                 Bp + (size_t)l * BPL,
                                                 selfb + (size_t)l * H, neighb + (size_t)l * H,
                                                 lng + (size_t)l * H, lnb + (size_t)l * H,
                                                 nmask, xh, xl);
    }

    k_pool1<<<dim3(B, PCHUNK), H, 0, stream>>>(xh, nmask, part);
    k_tail<<<B, 256, 0, stream>>>(part, W1, b1, W2, b2, out);
}

// Round 11
// 283.283 us; speedup vs baseline: 1.6454x; 1.1503x over previous
//
#include <hip/hip_runtime.h>
#include <hip/hip_bf16.h>

#define B 8
#define N 8192
#define E 65536
#define FIN 64
#define H 128
#define OUTD 256
#define NLAYER 3
#define EPS 1e-5f
#define PCHUNK 64
#define PNODES (N / PCHUNK)
#define NNODE (B * N)            // 65536 rows
#define KSTEPS 8                 // 2 groups x 4 k-steps of K=32 (xh*sWhi, nh*nWhi)
#define BPL (KSTEPS * 8 * 512)   // Bp ushort elems per layer
#define INSTEPS 6                // inproj: 3 groups x 2 k-steps (fh*Whi, fl*Whi, fh*Wlo)
#define ELLW 48                  // max incoming edges/node (Poisson(8): P(>48) ~ 1e-25)

#define AS1 __attribute__((address_space(1)))
#define AS3 __attribute__((address_space(3)))

typedef float f32x4 __attribute__((ext_vector_type(4)));
typedef __bf16 bf16x8 __attribute__((ext_vector_type(8)));

__device__ __forceinline__ float b2f(unsigned short u) {
    union { float f; unsigned int i; } c; c.i = ((unsigned int)u) << 16; return c.f;
}
__device__ __forceinline__ unsigned short f2b(float f) {
    __hip_bfloat16 h = __float2bfloat16(f);          // RTNE
    return *reinterpret_cast<unsigned short*>(&h);
}

// ---------------- unified weight pre-pack (layers + inproj) ----------------
// Layer groups (hi only): 0 xh*sWhi, 1 nh*nWhi
// Inproj groups: 0 fh*Whi, 1 fl*Whi, 2 fh*Wlo
__global__ void k_prep(const float* __restrict__ selfW, const float* __restrict__ neighW,
                       const float* __restrict__ inW,
                       unsigned short* __restrict__ Bp, unsigned short* __restrict__ Bpi) {
    const int idx = blockIdx.x;
    const int lane = threadIdx.x;
    const int quad = lane >> 4, col = lane & 15;
    if (idx < NLAYER * KSTEPS * 8) {
        const int t = idx & 7;
        const int s = (idx >> 3) % KSTEPS;
        const int l = idx / (KSTEPS * 8);
        const int g = s >> 2;
        const float* W = ((g == 0) ? selfW : neighW) + (size_t)l * H * H;
        const int n = t * 16 + col;
        unsigned short* dst = Bp + ((size_t)(l * KSTEPS + s) * 8 + t) * 512 + lane * 8;
        #pragma unroll
        for (int j = 0; j < 8; ++j) {
            const int kk = (s & 3) * 32 + quad * 8 + j;
            dst[j] = f2b(W[kk * H + n]);
        }
    } else {
        const int idx2 = idx - NLAYER * KSTEPS * 8;
        const int t = idx2 & 7;
        const int s = idx2 >> 3;                     // 0..5
        const int g = s >> 1;
        const bool lo = (g == 2);
        const int n = t * 16 + col;
        unsigned short* dst = Bpi + ((size_t)(s * 8 + t)) * 512 + lane * 8;
        #pragma unroll
        for (int j = 0; j < 8; ++j) {
            const int kk = (s & 1) * 32 + quad * 8 + j;   // K = 64
            const float w = inW[kk * H + n];
            const unsigned short hi = f2b(w);
            dst[j] = lo ? f2b(w - b2f(hi)) : hi;
        }
    }
}

// ---------------- input projection via MFMA: x = relu(feats @ inW + b) -> bf16 ----------------
// 1024 blocks x 4 waves; wave (mg,nw): m-tiles mg*2..+1, n-tiles nw*4..+3.
__global__ __launch_bounds__(256) void k_inproj5(const float* __restrict__ feats,
                                                 const unsigned short* __restrict__ Bpi,
                                                 const float* __restrict__ bias,
                                                 unsigned short* __restrict__ xh) {
    const int tid = threadIdx.x;
    const int wv = tid >> 6, lane = tid & 63;
    const int quad = lane >> 4, col = lane & 15;
    const int mg = wv >> 1, nw = wv & 1;
    const int row0 = blockIdx.x * 64;

    bf16x8 fh[2][2], fl[2][2];
    #pragma unroll
    for (int mt = 0; mt < 2; ++mt) {
        const int row = row0 + (mg * 2 + mt) * 16 + col;
        #pragma unroll
        for (int j = 0; j < 2; ++j) {
            const float* src = &feats[(size_t)row * FIN + j * 32 + quad * 8];
            const float4 v0 = *(const float4*)src;
            const float4 v1 = *(const float4*)(src + 4);
            const float fv[8] = {v0.x, v0.y, v0.z, v0.w, v1.x, v1.y, v1.z, v1.w};
            union { bf16x8 v; unsigned short u[8]; } Hh, Ll;
            #pragma unroll
            for (int q = 0; q < 8; ++q) {
                const unsigned short hu = f2b(fv[q]);
                Hh.u[q] = hu;
                Ll.u[q] = f2b(fv[q] - b2f(hu));
            }
            fh[mt][j] = Hh.v;
            fl[mt][j] = Ll.v;
        }
    }

    f32x4 acc[2][4] = {};
    bf16x8 bC[4];
    #pragma unroll
    for (int nt = 0; nt < 4; ++nt)
        bC[nt] = *(const bf16x8*)&Bpi[((size_t)(nw * 4 + nt)) * 512 + lane * 8];

    #pragma unroll
    for (int s = 0; s < INSTEPS; ++s) {
        bf16x8 bN[4];
        if (s + 1 < INSTEPS) {
            #pragma unroll
            for (int nt = 0; nt < 4; ++nt)
                bN[nt] = *(const bf16x8*)&Bpi[((size_t)(s + 1) * 8 + nw * 4 + nt) * 512 + lane * 8];
        }
        const int g = s >> 1, j = s & 1;
        #pragma unroll
        for (int mt = 0; mt < 2; ++mt) {
            const bf16x8 a = (g == 1) ? fl[mt][j] : fh[mt][j];
            #pragma unroll
            for (int nt = 0; nt < 4; ++nt)
                acc[mt][nt] = __builtin_amdgcn_mfma_f32_16x16x32_bf16(a, bC[nt], acc[mt][nt], 0, 0, 0);
        }
        #pragma unroll
        for (int nt = 0; nt < 4; ++nt) bC[nt] = bN[nt];
    }

    #pragma unroll
    for (int nt = 0; nt < 4; ++nt) {
        const int hh = (nw * 4 + nt) * 16 + col;
        const float bv = bias[hh];
        #pragma unroll
        for (int mt = 0; mt < 2; ++mt)
            #pragma unroll
            for (int r = 0; r < 4; ++r) {
                const int row = row0 + (mg * 2 + mt) * 16 + quad * 4 + r;
                const float y = fmaxf(acc[mt][nt][r] + bv, 0.f);
                xh[(size_t)row * H + hh] = f2b(y);
            }
    }
}

// ---------------- ELL build: packed 32-bit entries (mask bf16 << 16 | src) ----------------
__global__ void k_fill_ell(const int* __restrict__ ei, const float* __restrict__ emask,
                           int* __restrict__ ecnt, unsigned int* __restrict__ ell) {
    const int ge = blockIdx.x * 256 + threadIdx.x;       // b*E + e
    const float m = emask[ge];
    if (m > 0.f) {
        const int b = ge >> 16, e = ge & 0xFFFF;
        const int tgt = ei[(b * 2 + 1) * E + e];
        const int src = ei[(b * 2) * E + e];             // 0..N-1, fits 13 bits
        const int r = b * N + tgt;
        const int p = atomicAdd(&ecnt[r], 1);
        if (p < ELLW)
            ell[(size_t)r * ELLW + p] = ((unsigned int)f2b(m) << 16) | (unsigned int)src;
    }
}

// ---------------- gather from ELL: one wave per row, unroll-4, packed entries ----------------
__global__ __launch_bounds__(256) void k_gather6(const unsigned int* __restrict__ xh32,
                                                 const int* __restrict__ ecnt,
                                                 const unsigned int* __restrict__ ell,
                                                 unsigned int* __restrict__ nh32) {
    const int beta = blockIdx.x;               // 0..16383
    const int b = beta & 7;
    const int grp = beta >> 3;                 // 0..2047
    const int wave = threadIdx.x >> 6, lane = threadIdx.x & 63;
    const int r = b * N + grp * 4 + wave;
    const int cnt = min(ecnt[r], ELLW);
    unsigned int pv = 0;                       // mask 0 -> contributes nothing
    if (lane < cnt) pv = ell[(size_t)r * ELLW + lane];
    const size_t bbase = (size_t)b * N * 64;
    float a0 = 0.f, a1 = 0.f, c = 0.f;
    const int cnt4 = (cnt + 3) & ~3;
    for (int jj = 0; jj < cnt4; jj += 4) {
        #pragma unroll
        for (int q = 0; q < 4; ++q) {
            const unsigned int pk = __shfl(pv, jj + q);
            const float m = b2f((unsigned short)(pk >> 16));
            const unsigned int u = xh32[bbase + (size_t)(pk & 0xFFFFu) * 64 + lane];
            union { unsigned int i; float f; } lo, hi;
            lo.i = u << 16;
            hi.i = u & 0xFFFF0000u;
            a0 = fmaf(lo.f, m, a0);
            a1 = fmaf(hi.f, m, a1);
            c += m;
        }
    }
    const float inv = 1.f / fmaxf(c, 1.f);
    nh32[(size_t)r * 64 + lane] = (unsigned int)f2b(a0 * inv) | ((unsigned int)f2b(a1 * inv) << 16);
}

// ---------------- fused layer v8: LDS-staged B, KSTEPS=8, 4 chunks ----------------
// 1024 blocks x 4 waves. wave w: mg=w>>1 (m-tiles mg*2,mg*2+1), nw=w&1 (n-tiles nw*4..+3).
// chunk c (2 k-steps, 16 KB B) double-buffered via global_load_lds(16B); A register-prefetched.
// In-place on xh: block touches only its 64 rows.
__global__ __launch_bounds__(256) void k_layer8(const unsigned short* __restrict__ xinh,
                                                const unsigned short* __restrict__ nh,
                                                const unsigned short* __restrict__ Bp,
                                                const float* __restrict__ sb,
                                                const float* __restrict__ nb,
                                                const float* __restrict__ lng,
                                                const float* __restrict__ lnb,
                                                const float* __restrict__ nmask,
                                                unsigned short* __restrict__ oxh) {
    __shared__ __align__(16) unsigned short bbuf[2][16 * 512];   // 2 x 16 KB
    __shared__ float lsum[2][64];
    __shared__ float lsq[2][64];

    const int tid = threadIdx.x;
    const int wv = tid >> 6, lane = tid & 63;
    const int quad = lane >> 4, col = lane & 15;
    const int mg = wv >> 1, nw = wv & 1;
    const int u = blockIdx.x;
    const int b = u & 7;
    const int row0 = b * N + (u >> 3) * 64;       // batch-pinned to XCD b

    size_t abase[2];
    #pragma unroll
    for (int mt = 0; mt < 2; ++mt)
        abase[mt] = (size_t)(row0 + (mg * 2 + mt) * 16 + col) * H + quad * 8;

    // stage chunk 0 B (steps 0,1 -> tiles 0..15; wave wv stages tiles wv*4..+3)
    #pragma unroll
    for (int i = 0; i < 4; ++i) {
        const unsigned short* g = Bp + (size_t)(wv * 4 + i) * 512 + lane * 8;
        __builtin_amdgcn_global_load_lds((const AS1 unsigned int*)g,
                                         (AS3 unsigned int*)&bbuf[0][(wv * 4 + i) * 512],
                                         16, 0, 0);
    }
    // prefetch A chunk 0 (group 0 = xh; steps 0,1 -> ko 0,32)
    bf16x8 aC[2][2];
    #pragma unroll
    for (int j = 0; j < 2; ++j)
        #pragma unroll
        for (int mt = 0; mt < 2; ++mt)
            aC[j][mt] = *(const bf16x8*)&xinh[abase[mt] + j * 32];

    f32x4 acc[2][4] = {};

    #pragma unroll
    for (int c = 0; c < 4; ++c) {
        __syncthreads();                     // chunk c staged; buf[(c+1)&1] free
        bf16x8 aN[2][2];
        if (c < 3) {
            const int c1 = c + 1;
            #pragma unroll
            for (int i = 0; i < 4; ++i) {
                const unsigned short* g = Bp + (size_t)(c1 * 16 + wv * 4 + i) * 512 + lane * 8;
                __builtin_amdgcn_global_load_lds((const AS1 unsigned int*)g,
                                                 (AS3 unsigned int*)&bbuf[c1 & 1][(wv * 4 + i) * 512],
                                                 16, 0, 0);
            }
            const unsigned short* A1 = (c1 < 2) ? xinh : nh;   // steps 0-3: xh, 4-7: nh
            #pragma unroll
            for (int j = 0; j < 2; ++j)
                #pragma unroll
                for (int mt = 0; mt < 2; ++mt)
                    aN[j][mt] = *(const bf16x8*)&A1[abase[mt] + ((c1 & 1) * 2 + j) * 32];
        }
        #pragma unroll
        for (int j = 0; j < 2; ++j) {
            bf16x8 bf[4];
            #pragma unroll
            for (int nt = 0; nt < 4; ++nt)
                bf[nt] = *(const bf16x8*)&bbuf[c & 1][(j * 8 + nw * 4 + nt) * 512 + lane * 8];
            #pragma unroll
            for (int mt = 0; mt < 2; ++mt)
                #pragma unroll
                for (int nt = 0; nt < 4; ++nt)
                    acc[mt][nt] = __builtin_amdgcn_mfma_f32_16x16x32_bf16(aC[j][mt], bf[nt], acc[mt][nt], 0, 0, 0);
        }
        #pragma unroll
        for (int j = 0; j < 2; ++j)
            #pragma unroll
            for (int mt = 0; mt < 2; ++mt)
                aC[j][mt] = aN[j][mt];
    }

    // bias + relu (C/D: row = quad*4 + r, col = lane&15; h = (nw*4+nt)*16 + col)
    float sbv[4], nbv[4], gv[4], bbv[4];
    #pragma unroll
    for (int nt = 0; nt < 4; ++nt) {
        const int hh = (nw * 4 + nt) * 16 + col;
        sbv[nt] = sb[hh]; nbv[nt] = nb[hh]; gv[nt] = lng[hh]; bbv[nt] = lnb[hh];
    }
    #pragma unroll
    for (int mt = 0; mt < 2; ++mt)
        #pragma unroll
        for (int nt = 0; nt < 4; ++nt)
            #pragma unroll
            for (int r = 0; r < 4; ++r)
                acc[mt][nt][r] = fmaxf(acc[mt][nt][r] + sbv[nt] + nbv[nt], 0.f);

    // LN partials: wave covers 64 of 128 h for its 32 rows
    #pragma unroll
    for (int mt = 0; mt < 2; ++mt)
        #pragma unroll
        for (int r = 0; r < 4; ++r) {
            float p = 0.f, q = 0.f;
            #pragma unroll
            for (int nt = 0; nt < 4; ++nt) {
                const float v = acc[mt][nt][r];
                p += v;
                q = fmaf(v, v, q);
            }
            p += __shfl_xor(p, 1);  q += __shfl_xor(q, 1);
            p += __shfl_xor(p, 2);  q += __shfl_xor(q, 2);
            p += __shfl_xor(p, 4);  q += __shfl_xor(q, 4);
            p += __shfl_xor(p, 8);  q += __shfl_xor(q, 8);
            if (col == 0) {
                const int rib = (mg * 2 + mt) * 16 + quad * 4 + r;
                lsum[nw][rib] = p;
                lsq[nw][rib] = q;
            }
        }
    __syncthreads();   // all A-reads done before in-place stores

    #pragma unroll
    for (int mt = 0; mt < 2; ++mt)
        #pragma unroll
        for (int r = 0; r < 4; ++r) {
            const int rib = (mg * 2 + mt) * 16 + quad * 4 + r;
            const int node = row0 + rib;
            const float mu = (lsum[0][rib] + lsum[1][rib]) * (1.f / H);
            const float var = (lsq[0][rib] + lsq[1][rib]) * (1.f / H) - mu * mu;
            const float isd = rsqrtf(var + EPS);
            const float m = nmask[node];
            #pragma unroll
            for (int nt = 0; nt < 4; ++nt) {
                const float y = (fmaf(acc[mt][nt][r] - mu, isd * gv[nt], bbv[nt])) * m;
                oxh[(size_t)node * H + (nw * 4 + nt) * 16 + col] = f2b(y);
            }
        }
}

// ---------------- pooling partials (bf16 x) ----------------
__global__ void k_pool1(const unsigned short* __restrict__ xh,
                        const float* __restrict__ nmask, float* __restrict__ part) {
    const int b = blockIdx.x, c = blockIdx.y, h = threadIdx.x;
    const int n0 = c * PNODES;
    float s = 0.f, mx = -INFINITY, nv = 0.f;
    for (int it = 0; it < PNODES; ++it) {
        const int n = n0 + it;
        const float m = nmask[b * N + n];
        const float v = b2f(xh[((size_t)b * N + n) * H + h]) * m;
        s += v;
        if (m > 0.f) mx = fmaxf(mx, v);
        nv += m;
    }
    float* p = part + ((size_t)b * PCHUNK + c) * (2 * H + 1);
    p[h] = s;
    p[H + h] = mx;
    if (h == 0) p[2 * H] = nv;
}

// ---------------- fused pool-reduce + MLP head ----------------
__global__ __launch_bounds__(256) void k_tail(const float* __restrict__ part,
                                              const float* __restrict__ W1, const float* __restrict__ b1,
                                              const float* __restrict__ W2, const float* __restrict__ b2,
                                              float* __restrict__ out) {
    const int b = blockIdx.x, t = threadIdx.x;
    __shared__ float g[2 * H];
    __shared__ float hid[H];
    {
        float nv = 0.f;
        for (int c = 0; c < PCHUNK; ++c)
            nv += part[((size_t)b * PCHUNK + c) * (2 * H + 1) + 2 * H];
        if (t < H) {
            float s = 0.f;
            for (int c = 0; c < PCHUNK; ++c)
                s += part[((size_t)b * PCHUNK + c) * (2 * H + 1) + t];
            g[t] = s / fmaxf(nv, 1.f);
        } else {
            const int h = t - H;
            float mx = -INFINITY;
            for (int c = 0; c < PCHUNK; ++c)
                mx = fmaxf(mx, part[((size_t)b * PCHUNK + c) * (2 * H + 1) + H + h]);
            g[t] = mx;
        }
    }
    __syncthreads();
    if (t < H) {
        float a = b1[t];
        #pragma unroll 8
        for (int k = 0; k < 2 * H; ++k) a = fmaf(g[k], W1[k * H + t], a);
        hid[t] = fmaxf(a, 0.f);
    }
    __syncthreads();
    float a = b2[t];
    #pragma unroll 8
    for (int k = 0; k < H; ++k) a = fmaf(hid[k], W2[k * OUTD + t], a);
    out[(size_t)b * OUTD + t] = a;
}

extern "C" void kernel_launch(void* const* d_in, const int* in_sizes, int n_in,
                              void* d_out, int out_size, void* d_ws, size_t ws_size,
                              hipStream_t stream) {
    const float* feats = (const float*)d_in[0];
    const int*   ei    = (const int*)d_in[1];
    const float* nmask = (const float*)d_in[2];
    const float* emask = (const float*)d_in[3];
    const float* inW   = (const float*)d_in[4];
    const float* inb   = (const float*)d_in[5];
    const float* selfW = (const float*)d_in[6];
    const float* selfb = (const float*)d_in[7];
    const float* neighW= (const float*)d_in[8];
    const float* neighb= (const float*)d_in[9];
    const float* lng   = (const float*)d_in[10];
    const float* lnb   = (const float*)d_in[11];
    const float* W1    = (const float*)d_in[12];
    const float* b1    = (const float*)d_in[13];
    const float* W2    = (const float*)d_in[14];
    const float* b2    = (const float*)d_in[15];
    float* out = (float*)d_out;

    const size_t nxh = (size_t)NNODE * H;
    char* w = (char*)d_ws;
    unsigned short* xh  = (unsigned short*)w;  w += nxh * 2;
    unsigned short* nh  = (unsigned short*)w;  w += nxh * 2;
    unsigned short* Bp  = (unsigned short*)w;  w += (size_t)NLAYER * BPL * 2;
    unsigned short* Bpi = (unsigned short*)w;  w += (size_t)INSTEPS * 8 * 512 * 2;
    float* part = (float*)w;                   w += (size_t)B * PCHUNK * (2 * H + 1) * 4;
    int* ecnt   = (int*)w;                     w += (size_t)NNODE * 4;
    unsigned int* ell = (unsigned int*)w;      w += (size_t)NNODE * ELLW * 4;

    k_prep<<<NLAYER * KSTEPS * 8 + INSTEPS * 8, 64, 0, stream>>>(selfW, neighW, inW, Bp, Bpi);
    k_inproj5<<<NNODE / 64, 256, 0, stream>>>(feats, Bpi, inb, xh);

    hipMemsetAsync(ecnt, 0, (size_t)NNODE * sizeof(int), stream);
    k_fill_ell<<<B * E / 256, 256, 0, stream>>>(ei, emask, ecnt, ell);

    for (int l = 0; l < NLAYER; ++l) {
        k_gather6<<<NNODE / 4, 256, 0, stream>>>((const unsigned int*)xh, ecnt, ell,
                                                 (unsigned int*)nh);
        k_layer8<<<NNODE / 64, 256, 0, stream>>>(xh, nh,
                                                 Bp + (size_t)l * BPL,
                                                 selfb + (size_t)l * H, neighb + (size_t)l * H,
                                                 lng + (size_t)l * H, lnb + (size_t)l * H,
                                                 nmask, xh);
    }

    k_pool1<<<dim3(B, PCHUNK), H, 0, stream>>>(xh, nmask, part);
    k_tail<<<B, 256, 0, stream>>>(part, W1, b1, W2, b2, out);
}

// Round 12
// 280.437 us; speedup vs baseline: 1.6621x; 1.0101x over previous
//
#include <hip/hip_runtime.h>
#include <hip/hip_bf16.h>

#define B 8
#define N 8192
#define E 65536
#define FIN 64
#define H 128
#define OUTD 256
#define NLAYER 3
#define EPS 1e-5f
#define NCHUNK 128               // pool chunks per batch (one per layer block)
#define NNODE (B * N)            // 65536 rows
#define KSTEPS 8                 // 2 groups x 4 k-steps of K=32 (xh*sWhi, nh*nWhi)
#define BPL (KSTEPS * 8 * 512)   // Bp ushort elems per layer
#define INSTEPS 6                // inproj: 3 groups x 2 k-steps (fh*Whi, fl*Whi, fh*Wlo)
#define ELLW 48                  // max incoming edges/node (Poisson(8): P(>48) ~ 1e-25)

#define AS1 __attribute__((address_space(1)))
#define AS3 __attribute__((address_space(3)))

typedef float f32x4 __attribute__((ext_vector_type(4)));
typedef __bf16 bf16x8 __attribute__((ext_vector_type(8)));

__device__ __forceinline__ float b2f(unsigned short u) {
    union { float f; unsigned int i; } c; c.i = ((unsigned int)u) << 16; return c.f;
}
__device__ __forceinline__ unsigned short f2b(float f) {
    __hip_bfloat16 h = __float2bfloat16(f);          // RTNE
    return *reinterpret_cast<unsigned short*>(&h);
}

// ---------------- unified weight pre-pack (layers + inproj) ----------------
__global__ void k_prep(const float* __restrict__ selfW, const float* __restrict__ neighW,
                       const float* __restrict__ inW,
                       unsigned short* __restrict__ Bp, unsigned short* __restrict__ Bpi) {
    const int idx = blockIdx.x;
    const int lane = threadIdx.x;
    const int quad = lane >> 4, col = lane & 15;
    if (idx < NLAYER * KSTEPS * 8) {
        const int t = idx & 7;
        const int s = (idx >> 3) % KSTEPS;
        const int l = idx / (KSTEPS * 8);
        const int g = s >> 2;
        const float* W = ((g == 0) ? selfW : neighW) + (size_t)l * H * H;
        const int n = t * 16 + col;
        unsigned short* dst = Bp + ((size_t)(l * KSTEPS + s) * 8 + t) * 512 + lane * 8;
        #pragma unroll
        for (int j = 0; j < 8; ++j) {
            const int kk = (s & 3) * 32 + quad * 8 + j;
            dst[j] = f2b(W[kk * H + n]);
        }
    } else {
        const int idx2 = idx - NLAYER * KSTEPS * 8;
        const int t = idx2 & 7;
        const int s = idx2 >> 3;                     // 0..5
        const int g = s >> 1;
        const bool lo = (g == 2);
        const int n = t * 16 + col;
        unsigned short* dst = Bpi + ((size_t)(s * 8 + t)) * 512 + lane * 8;
        #pragma unroll
        for (int j = 0; j < 8; ++j) {
            const int kk = (s & 1) * 32 + quad * 8 + j;   // K = 64
            const float w = inW[kk * H + n];
            const unsigned short hi = f2b(w);
            dst[j] = lo ? f2b(w - b2f(hi)) : hi;
        }
    }
}

// ---------------- fat kernel: inproj (blocks 0..1023) || ELL fill (blocks 1024..3071) ----------------
__global__ __launch_bounds__(256) void k_front(const float* __restrict__ feats,
                                               const unsigned short* __restrict__ Bpi,
                                               const float* __restrict__ bias,
                                               unsigned short* __restrict__ xh,
                                               const int* __restrict__ ei,
                                               const float* __restrict__ emask,
                                               int* __restrict__ ecnt,
                                               unsigned int* __restrict__ ell) {
    const int tid = threadIdx.x;
    if (blockIdx.x >= 1024) {
        // ---- ELL fill: packed entry (mask bf16 << 16 | src) ----
        const int ge = (blockIdx.x - 1024) * 256 + tid;      // b*E + e
        const float m = emask[ge];
        if (m > 0.f) {
            const int b = ge >> 16, e = ge & 0xFFFF;
            const int tgt = ei[(b * 2 + 1) * E + e];
            const int src = ei[(b * 2) * E + e];
            const int r = b * N + tgt;
            const int p = atomicAdd(&ecnt[r], 1);
            if (p < ELLW)
                ell[(size_t)r * ELLW + p] = ((unsigned int)f2b(m) << 16) | (unsigned int)src;
        }
        return;
    }
    // ---- input projection via MFMA -> bf16 x ----
    const int wv = tid >> 6, lane = tid & 63;
    const int quad = lane >> 4, col = lane & 15;
    const int mg = wv >> 1, nw = wv & 1;
    const int row0 = blockIdx.x * 64;

    bf16x8 fh[2][2], fl[2][2];
    #pragma unroll
    for (int mt = 0; mt < 2; ++mt) {
        const int row = row0 + (mg * 2 + mt) * 16 + col;
        #pragma unroll
        for (int j = 0; j < 2; ++j) {
            const float* src = &feats[(size_t)row * FIN + j * 32 + quad * 8];
            const float4 v0 = *(const float4*)src;
            const float4 v1 = *(const float4*)(src + 4);
            const float fv[8] = {v0.x, v0.y, v0.z, v0.w, v1.x, v1.y, v1.z, v1.w};
            union { bf16x8 v; unsigned short u[8]; } Hh, Ll;
            #pragma unroll
            for (int q = 0; q < 8; ++q) {
                const unsigned short hu = f2b(fv[q]);
                Hh.u[q] = hu;
                Ll.u[q] = f2b(fv[q] - b2f(hu));
            }
            fh[mt][j] = Hh.v;
            fl[mt][j] = Ll.v;
        }
    }

    f32x4 acc[2][4] = {};
    bf16x8 bC[4];
    #pragma unroll
    for (int nt = 0; nt < 4; ++nt)
        bC[nt] = *(const bf16x8*)&Bpi[((size_t)(nw * 4 + nt)) * 512 + lane * 8];

    #pragma unroll
    for (int s = 0; s < INSTEPS; ++s) {
        bf16x8 bN[4];
        if (s + 1 < INSTEPS) {
            #pragma unroll
            for (int nt = 0; nt < 4; ++nt)
                bN[nt] = *(const bf16x8*)&Bpi[((size_t)(s + 1) * 8 + nw * 4 + nt) * 512 + lane * 8];
        }
        const int g = s >> 1, j = s & 1;
        #pragma unroll
        for (int mt = 0; mt < 2; ++mt) {
            const bf16x8 a = (g == 1) ? fl[mt][j] : fh[mt][j];
            #pragma unroll
            for (int nt = 0; nt < 4; ++nt)
                acc[mt][nt] = __builtin_amdgcn_mfma_f32_16x16x32_bf16(a, bC[nt], acc[mt][nt], 0, 0, 0);
        }
        #pragma unroll
        for (int nt = 0; nt < 4; ++nt) bC[nt] = bN[nt];
    }

    #pragma unroll
    for (int nt = 0; nt < 4; ++nt) {
        const int hh = (nw * 4 + nt) * 16 + col;
        const float bv = bias[hh];
        #pragma unroll
        for (int mt = 0; mt < 2; ++mt)
            #pragma unroll
            for (int r = 0; r < 4; ++r) {
                const int row = row0 + (mg * 2 + mt) * 16 + quad * 4 + r;
                const float y = fmaxf(acc[mt][nt][r] + bv, 0.f);
                xh[(size_t)row * H + hh] = f2b(y);
            }
    }
}

// ---------------- gather: speculative ELL read, unroll-8, one wave per row ----------------
__global__ __launch_bounds__(256) void k_gather7(const unsigned int* __restrict__ xh32,
                                                 const int* __restrict__ ecnt,
                                                 const unsigned int* __restrict__ ell,
                                                 unsigned int* __restrict__ nh32) {
    const int beta = blockIdx.x;               // 0..16383
    const int b = beta & 7;
    const int grp = beta >> 3;                 // 0..2047
    const int wave = threadIdx.x >> 6, lane = threadIdx.x & 63;
    const int r = b * N + grp * 4 + wave;
    // speculative: ELL row and count load concurrently (no dependent chain)
    unsigned int pv = 0;
    if (lane < ELLW) pv = ell[(size_t)r * ELLW + lane];
    const int cnt = min(ecnt[r], ELLW);
    if (lane >= cnt) pv = 0;                   // mask garbage; mask 0 contributes nothing
    const size_t bbase = (size_t)b * N * 64;
    float a0 = 0.f, a1 = 0.f, c = 0.f;
    const int cnt8 = (cnt + 7) & ~7;
    for (int jj = 0; jj < cnt8; jj += 8) {
        #pragma unroll
        for (int q = 0; q < 8; ++q) {
            const unsigned int pk = __shfl(pv, jj + q);
            const float m = b2f((unsigned short)(pk >> 16));
            const unsigned int u = xh32[bbase + (size_t)(pk & 0xFFFFu) * 64 + lane];
            union { unsigned int i; float f; } lo, hi;
            lo.i = u << 16;
            hi.i = u & 0xFFFF0000u;
            a0 = fmaf(lo.f, m, a0);
            a1 = fmaf(hi.f, m, a1);
            c += m;
        }
    }
    const float inv = 1.f / fmaxf(c, 1.f);
    nh32[(size_t)r * 64 + lane] = (unsigned int)f2b(a0 * inv) | ((unsigned int)f2b(a1 * inv) << 16);
}

// ---------------- fused layer v9: LDS-staged B; last layer emits pool partials ----------------
// 1024 blocks x 4 waves. wave w: mg=w>>1, nw=w&1. In-place on xh (non-last); last: pool partials only.
__global__ __launch_bounds__(256) void k_layer9(const unsigned short* __restrict__ xinh,
                                                const unsigned short* __restrict__ nh,
                                                const unsigned short* __restrict__ Bp,
                                                const float* __restrict__ sb,
                                                const float* __restrict__ nb,
                                                const float* __restrict__ lng,
                                                const float* __restrict__ lnb,
                                                const float* __restrict__ nmask,
                                                unsigned short* __restrict__ oxh,
                                                float* __restrict__ part,
                                                const int last) {
    __shared__ __align__(16) unsigned short bbuf[2][16 * 512];   // 2 x 16 KB
    __shared__ float lsum[2][64];
    __shared__ float lsq[2][64];
    __shared__ float psum_s[2][H];
    __shared__ float pmax_s[2][H];

    const int tid = threadIdx.x;
    const int wv = tid >> 6, lane = tid & 63;
    const int quad = lane >> 4, col = lane & 15;
    const int mg = wv >> 1, nw = wv & 1;
    const int u = blockIdx.x;
    const int b = u & 7;
    const int chunk = u >> 3;                     // 0..127
    const int row0 = b * N + chunk * 64;          // batch-pinned to XCD b

    size_t abase[2];
    #pragma unroll
    for (int mt = 0; mt < 2; ++mt)
        abase[mt] = (size_t)(row0 + (mg * 2 + mt) * 16 + col) * H + quad * 8;

    #pragma unroll
    for (int i = 0; i < 4; ++i) {
        const unsigned short* g = Bp + (size_t)(wv * 4 + i) * 512 + lane * 8;
        __builtin_amdgcn_global_load_lds((const AS1 unsigned int*)g,
                                         (AS3 unsigned int*)&bbuf[0][(wv * 4 + i) * 512],
                                         16, 0, 0);
    }
    bf16x8 aC[2][2];
    #pragma unroll
    for (int j = 0; j < 2; ++j)
        #pragma unroll
        for (int mt = 0; mt < 2; ++mt)
            aC[j][mt] = *(const bf16x8*)&xinh[abase[mt] + j * 32];

    f32x4 acc[2][4] = {};

    #pragma unroll
    for (int c = 0; c < 4; ++c) {
        __syncthreads();
        bf16x8 aN[2][2];
        if (c < 3) {
            const int c1 = c + 1;
            #pragma unroll
            for (int i = 0; i < 4; ++i) {
                const unsigned short* g = Bp + (size_t)(c1 * 16 + wv * 4 + i) * 512 + lane * 8;
                __builtin_amdgcn_global_load_lds((const AS1 unsigned int*)g,
                                                 (AS3 unsigned int*)&bbuf[c1 & 1][(wv * 4 + i) * 512],
                                                 16, 0, 0);
            }
            const unsigned short* A1 = (c1 < 2) ? xinh : nh;   // steps 0-3: xh, 4-7: nh
            #pragma unroll
            for (int j = 0; j < 2; ++j)
                #pragma unroll
                for (int mt = 0; mt < 2; ++mt)
                    aN[j][mt] = *(const bf16x8*)&A1[abase[mt] + ((c1 & 1) * 2 + j) * 32];
        }
        #pragma unroll
        for (int j = 0; j < 2; ++j) {
            bf16x8 bf[4];
            #pragma unroll
            for (int nt = 0; nt < 4; ++nt)
                bf[nt] = *(const bf16x8*)&bbuf[c & 1][(j * 8 + nw * 4 + nt) * 512 + lane * 8];
            #pragma unroll
            for (int mt = 0; mt < 2; ++mt)
                #pragma unroll
                for (int nt = 0; nt < 4; ++nt)
                    acc[mt][nt] = __builtin_amdgcn_mfma_f32_16x16x32_bf16(aC[j][mt], bf[nt], acc[mt][nt], 0, 0, 0);
        }
        #pragma unroll
        for (int j = 0; j < 2; ++j)
            #pragma unroll
            for (int mt = 0; mt < 2; ++mt)
                aC[j][mt] = aN[j][mt];
    }

    // bias + relu
    float sbv[4], nbv[4], gv[4], bbv[4];
    #pragma unroll
    for (int nt = 0; nt < 4; ++nt) {
        const int hh = (nw * 4 + nt) * 16 + col;
        sbv[nt] = sb[hh]; nbv[nt] = nb[hh]; gv[nt] = lng[hh]; bbv[nt] = lnb[hh];
    }
    #pragma unroll
    for (int mt = 0; mt < 2; ++mt)
        #pragma unroll
        for (int nt = 0; nt < 4; ++nt)
            #pragma unroll
            for (int r = 0; r < 4; ++r)
                acc[mt][nt][r] = fmaxf(acc[mt][nt][r] + sbv[nt] + nbv[nt], 0.f);

    // LN partials
    #pragma unroll
    for (int mt = 0; mt < 2; ++mt)
        #pragma unroll
        for (int r = 0; r < 4; ++r) {
            float p = 0.f, q = 0.f;
            #pragma unroll
            for (int nt = 0; nt < 4; ++nt) {
                const float v = acc[mt][nt][r];
                p += v;
                q = fmaf(v, v, q);
            }
            p += __shfl_xor(p, 1);  q += __shfl_xor(q, 1);
            p += __shfl_xor(p, 2);  q += __shfl_xor(q, 2);
            p += __shfl_xor(p, 4);  q += __shfl_xor(q, 4);
            p += __shfl_xor(p, 8);  q += __shfl_xor(q, 8);
            if (col == 0) {
                const int rib = (mg * 2 + mt) * 16 + quad * 4 + r;
                lsum[nw][rib] = p;
                lsq[nw][rib] = q;
            }
        }
    __syncthreads();   // all A-reads done before in-place stores

    float psum[4] = {0.f, 0.f, 0.f, 0.f};
    float pmax[4] = {-INFINITY, -INFINITY, -INFINITY, -INFINITY};

    #pragma unroll
    for (int mt = 0; mt < 2; ++mt)
        #pragma unroll
        for (int r = 0; r < 4; ++r) {
            const int rib = (mg * 2 + mt) * 16 + quad * 4 + r;
            const int node = row0 + rib;
            const float mu = (lsum[0][rib] + lsum[1][rib]) * (1.f / H);
            const float var = (lsq[0][rib] + lsq[1][rib]) * (1.f / H) - mu * mu;
            const float isd = rsqrtf(var + EPS);
            const float m = nmask[node];
            #pragma unroll
            for (int nt = 0; nt < 4; ++nt) {
                const float y = (fmaf(acc[mt][nt][r] - mu, isd * gv[nt], bbv[nt])) * m;
                if (!last) {
                    oxh[(size_t)node * H + (nw * 4 + nt) * 16 + col] = f2b(y);
                } else {
                    psum[nt] += y;
                    pmax[nt] = fmaxf(pmax[nt], (m > 0.f) ? y : -INFINITY);
                }
            }
        }

    if (last) {
        // reduce over quads (wave's 32 rows), stash per-mg, combine, write partials
        #pragma unroll
        for (int nt = 0; nt < 4; ++nt) {
            psum[nt] += __shfl_xor(psum[nt], 16);
            psum[nt] += __shfl_xor(psum[nt], 32);
            pmax[nt] = fmaxf(pmax[nt], __shfl_xor(pmax[nt], 16));
            pmax[nt] = fmaxf(pmax[nt], __shfl_xor(pmax[nt], 32));
        }
        if (quad == 0)
            #pragma unroll
            for (int nt = 0; nt < 4; ++nt) {
                psum_s[mg][(nw * 4 + nt) * 16 + col] = psum[nt];
                pmax_s[mg][(nw * 4 + nt) * 16 + col] = pmax[nt];
            }
        // nv: sum of nmask over the block's 64 rows (wave 0)
        float nv = 0.f;
        if (wv == 0) {
            nv = nmask[row0 + lane];
            nv += __shfl_xor(nv, 1);  nv += __shfl_xor(nv, 2);
            nv += __shfl_xor(nv, 4);  nv += __shfl_xor(nv, 8);
            nv += __shfl_xor(nv, 16); nv += __shfl_xor(nv, 32);
        }
        __syncthreads();
        float* p = part + ((size_t)b * NCHUNK + chunk) * (2 * H + 1);
        if (tid < H) {
            p[tid] = psum_s[0][tid] + psum_s[1][tid];
            p[H + tid] = fmaxf(pmax_s[0][tid], pmax_s[1][tid]);
        }
        if (tid == 0) p[2 * H] = nv;
    }
}

// ---------------- fused pool-reduce + MLP head ----------------
__global__ __launch_bounds__(256) void k_tail(const float* __restrict__ part,
                                              const float* __restrict__ W1, const float* __restrict__ b1,
                                              const float* __restrict__ W2, const float* __restrict__ b2,
                                              float* __restrict__ out) {
    const int b = blockIdx.x, t = threadIdx.x;
    __shared__ float g[2 * H];
    __shared__ float hid[H];
    {
        float nv = 0.f;
        for (int c = 0; c < NCHUNK; ++c)
            nv += part[((size_t)b * NCHUNK + c) * (2 * H + 1) + 2 * H];
        if (t < H) {
            float s = 0.f;
            for (int c = 0; c < NCHUNK; ++c)
                s += part[((size_t)b * NCHUNK + c) * (2 * H + 1) + t];
            g[t] = s / fmaxf(nv, 1.f);
        } else {
            const int h = t - H;
            float mx = -INFINITY;
            for (int c = 0; c < NCHUNK; ++c)
                mx = fmaxf(mx, part[((size_t)b * NCHUNK + c) * (2 * H + 1) + H + h]);
            g[t] = mx;
        }
    }
    __syncthreads();
    if (t < H) {
        float a = b1[t];
        #pragma unroll 8
        for (int k = 0; k < 2 * H; ++k) a = fmaf(g[k], W1[k * H + t], a);
        hid[t] = fmaxf(a, 0.f);
    }
    __syncthreads();
    float a = b2[t];
    #pragma unroll 8
    for (int k = 0; k < H; ++k) a = fmaf(hid[k], W2[k * OUTD + t], a);
    out[(size_t)b * OUTD + t] = a;
}

extern "C" void kernel_launch(void* const* d_in, const int* in_sizes, int n_in,
                              void* d_out, int out_size, void* d_ws, size_t ws_size,
                              hipStream_t stream) {
    const float* feats = (const float*)d_in[0];
    const int*   ei    = (const int*)d_in[1];
    const float* nmask = (const float*)d_in[2];
    const float* emask = (const float*)d_in[3];
    const float* inW   = (const float*)d_in[4];
    const float* inb   = (const float*)d_in[5];
    const float* selfW = (const float*)d_in[6];
    const float* selfb = (const float*)d_in[7];
    const float* neighW= (const float*)d_in[8];
    const float* neighb= (const float*)d_in[9];
    const float* lng   = (const float*)d_in[10];
    const float* lnb   = (const float*)d_in[11];
    const float* W1    = (const float*)d_in[12];
    const float* b1    = (const float*)d_in[13];
    const float* W2    = (const float*)d_in[14];
    const float* b2    = (const float*)d_in[15];
    float* out = (float*)d_out;

    const size_t nxh = (size_t)NNODE * H;
    char* w = (char*)d_ws;
    unsigned short* xh  = (unsigned short*)w;  w += nxh * 2;
    unsigned short* nh  = (unsigned short*)w;  w += nxh * 2;
    unsigned short* Bp  = (unsigned short*)w;  w += (size_t)NLAYER * BPL * 2;
    unsigned short* Bpi = (unsigned short*)w;  w += (size_t)INSTEPS * 8 * 512 * 2;
    float* part = (float*)w;                   w += (size_t)B * NCHUNK * (2 * H + 1) * 4;
    int* ecnt   = (int*)w;                     w += (size_t)NNODE * 4;
    unsigned int* ell = (unsigned int*)w;      w += (size_t)NNODE * ELLW * 4;

    k_prep<<<NLAYER * KSTEPS * 8 + INSTEPS * 8, 64, 0, stream>>>(selfW, neighW, inW, Bp, Bpi);
    hipMemsetAsync(ecnt, 0, (size_t)NNODE * sizeof(int), stream);
    k_front<<<1024 + B * E / 256, 256, 0, stream>>>(feats, Bpi, inb, xh, ei, emask, ecnt, ell);

    for (int l = 0; l < NLAYER; ++l) {
        k_gather7<<<NNODE / 4, 256, 0, stream>>>((const unsigned int*)xh, ecnt, ell,
                                                 (unsigned int*)nh);
        k_layer9<<<NNODE / 64, 256, 0, stream>>>(xh, nh,
                                                 Bp + (size_t)l * BPL,
                                                 selfb + (size_t)l * H, neighb + (size_t)l * H,
                                                 lng + (size_t)l * H, lnb + (size_t)l * H,
                                                 nmask, xh, part, (l == NLAYER - 1) ? 1 : 0);
    }

    k_tail<<<B, 256, 0, stream>>>(part, W1, b1, W2, b2, out);
}

// Round 13
// 253.110 us; speedup vs baseline: 1.8415x; 1.1080x over previous
//
#include <hip/hip_runtime.h>
#include <hip/hip_bf16.h>

#define B 8
#define N 8192
#define E 65536
#define FIN 64
#define H 128
#define OUTD 256
#define NLAYER 3
#define EPS 1e-5f
#define NCHUNK 128               // pool chunks per batch (one per layer block)
#define NNODE (B * N)            // 65536 rows
#define KSTEPS 8                 // 2 groups x 4 k-steps of K=32 (xh*sWhi, nh*nWhi)
#define BPL (KSTEPS * 8 * 512)   // Bp ushort elems per layer
#define INSTEPS 6                // inproj: 3 groups x 2 k-steps (fh*Whi, fl*Whi, fh*Wlo)
#define ELLW 48                  // max incoming edges/node (Poisson(8): P(>48) ~ 1e-25)

#define AS1 __attribute__((address_space(1)))
#define AS3 __attribute__((address_space(3)))

typedef float f32x4 __attribute__((ext_vector_type(4)));
typedef __bf16 bf16x8 __attribute__((ext_vector_type(8)));

__device__ __forceinline__ float b2f(unsigned short u) {
    union { float f; unsigned int i; } c; c.i = ((unsigned int)u) << 16; return c.f;
}
__device__ __forceinline__ unsigned short f2b(float f) {
    __hip_bfloat16 h = __float2bfloat16(f);          // RTNE
    return *reinterpret_cast<unsigned short*>(&h);
}

// ---------------- unified weight pre-pack (layers + inproj) ----------------
__global__ void k_prep(const float* __restrict__ selfW, const float* __restrict__ neighW,
                       const float* __restrict__ inW,
                       unsigned short* __restrict__ Bp, unsigned short* __restrict__ Bpi) {
    const int idx = blockIdx.x;
    const int lane = threadIdx.x;
    const int quad = lane >> 4, col = lane & 15;
    if (idx < NLAYER * KSTEPS * 8) {
        const int t = idx & 7;
        const int s = (idx >> 3) % KSTEPS;
        const int l = idx / (KSTEPS * 8);
        const int g = s >> 2;
        const float* W = ((g == 0) ? selfW : neighW) + (size_t)l * H * H;
        const int n = t * 16 + col;
        unsigned short* dst = Bp + ((size_t)(l * KSTEPS + s) * 8 + t) * 512 + lane * 8;
        #pragma unroll
        for (int j = 0; j < 8; ++j) {
            const int kk = (s & 3) * 32 + quad * 8 + j;
            dst[j] = f2b(W[kk * H + n]);
        }
    } else {
        const int idx2 = idx - NLAYER * KSTEPS * 8;
        const int t = idx2 & 7;
        const int s = idx2 >> 3;                     // 0..5
        const int g = s >> 1;
        const bool lo = (g == 2);
        const int n = t * 16 + col;
        unsigned short* dst = Bpi + ((size_t)(s * 8 + t)) * 512 + lane * 8;
        #pragma unroll
        for (int j = 0; j < 8; ++j) {
            const int kk = (s & 1) * 32 + quad * 8 + j;   // K = 64
            const float w = inW[kk * H + n];
            const unsigned short hi = f2b(w);
            dst[j] = lo ? f2b(w - b2f(hi)) : hi;
        }
    }
}

// ---------------- fat kernel: inproj (blocks 0..1023) || ELL fill (blocks 1024..3071) ----------------
__global__ __launch_bounds__(256) void k_front(const float* __restrict__ feats,
                                               const unsigned short* __restrict__ Bpi,
                                               const float* __restrict__ bias,
                                               unsigned short* __restrict__ xh,
                                               const int* __restrict__ ei,
                                               const float* __restrict__ emask,
                                               int* __restrict__ ecnt,
                                               unsigned int* __restrict__ ell) {
    const int tid = threadIdx.x;
    if (blockIdx.x >= 1024) {
        // ---- ELL fill: packed entry (mask bf16 << 16 | src) ----
        const int ge = (blockIdx.x - 1024) * 256 + tid;      // b*E + e
        const float m = emask[ge];
        if (m > 0.f) {
            const int b = ge >> 16, e = ge & 0xFFFF;
            const int tgt = ei[(b * 2 + 1) * E + e];
            const int src = ei[(b * 2) * E + e];
            const int r = b * N + tgt;
            const int p = atomicAdd(&ecnt[r], 1);
            if (p < ELLW)
                ell[(size_t)r * ELLW + p] = ((unsigned int)f2b(m) << 16) | (unsigned int)src;
        }
        return;
    }
    // ---- input projection via MFMA -> bf16 x ----
    const int wv = tid >> 6, lane = tid & 63;
    const int quad = lane >> 4, col = lane & 15;
    const int mg = wv >> 1, nw = wv & 1;
    const int row0 = blockIdx.x * 64;

    bf16x8 fh[2][2], fl[2][2];
    #pragma unroll
    for (int mt = 0; mt < 2; ++mt) {
        const int row = row0 + (mg * 2 + mt) * 16 + col;
        #pragma unroll
        for (int j = 0; j < 2; ++j) {
            const float* src = &feats[(size_t)row * FIN + j * 32 + quad * 8];
            const float4 v0 = *(const float4*)src;
            const float4 v1 = *(const float4*)(src + 4);
            const float fv[8] = {v0.x, v0.y, v0.z, v0.w, v1.x, v1.y, v1.z, v1.w};
            union { bf16x8 v; unsigned short u[8]; } Hh, Ll;
            #pragma unroll
            for (int q = 0; q < 8; ++q) {
                const unsigned short hu = f2b(fv[q]);
                Hh.u[q] = hu;
                Ll.u[q] = f2b(fv[q] - b2f(hu));
            }
            fh[mt][j] = Hh.v;
            fl[mt][j] = Ll.v;
        }
    }

    f32x4 acc[2][4] = {};
    bf16x8 bC[4];
    #pragma unroll
    for (int nt = 0; nt < 4; ++nt)
        bC[nt] = *(const bf16x8*)&Bpi[((size_t)(nw * 4 + nt)) * 512 + lane * 8];

    #pragma unroll
    for (int s = 0; s < INSTEPS; ++s) {
        bf16x8 bN[4];
        if (s + 1 < INSTEPS) {
            #pragma unroll
            for (int nt = 0; nt < 4; ++nt)
                bN[nt] = *(const bf16x8*)&Bpi[((size_t)(s + 1) * 8 + nw * 4 + nt) * 512 + lane * 8];
        }
        const int g = s >> 1, j = s & 1;
        #pragma unroll
        for (int mt = 0; mt < 2; ++mt) {
            const bf16x8 a = (g == 1) ? fl[mt][j] : fh[mt][j];
            #pragma unroll
            for (int nt = 0; nt < 4; ++nt)
                acc[mt][nt] = __builtin_amdgcn_mfma_f32_16x16x32_bf16(a, bC[nt], acc[mt][nt], 0, 0, 0);
        }
        #pragma unroll
        for (int nt = 0; nt < 4; ++nt) bC[nt] = bN[nt];
    }

    #pragma unroll
    for (int nt = 0; nt < 4; ++nt) {
        const int hh = (nw * 4 + nt) * 16 + col;
        const float bv = bias[hh];
        #pragma unroll
        for (int mt = 0; mt < 2; ++mt)
            #pragma unroll
            for (int r = 0; r < 4; ++r) {
                const int row = row0 + (mg * 2 + mt) * 16 + quad * 4 + r;
                const float y = fmaxf(acc[mt][nt][r] + bv, 0.f);
                xh[(size_t)row * H + hh] = f2b(y);
            }
    }
}

// ---------------- gather: speculative ELL read, unroll-8, one wave per row ----------------
__global__ __launch_bounds__(256) void k_gather7(const unsigned int* __restrict__ xh32,
                                                 const int* __restrict__ ecnt,
                                                 const unsigned int* __restrict__ ell,
                                                 unsigned int* __restrict__ nh32) {
    const int beta = blockIdx.x;               // 0..16383
    const int b = beta & 7;
    const int grp = beta >> 3;                 // 0..2047
    const int wave = threadIdx.x >> 6, lane = threadIdx.x & 63;
    const int r = b * N + grp * 4 + wave;
    // speculative: ELL row and count load concurrently (no dependent chain)
    unsigned int pv = 0;
    if (lane < ELLW) pv = ell[(size_t)r * ELLW + lane];
    const int cnt = min(ecnt[r], ELLW);
    if (lane >= cnt) pv = 0;                   // mask garbage; mask 0 contributes nothing
    const size_t bbase = (size_t)b * N * 64;
    float a0 = 0.f, a1 = 0.f, c = 0.f;
    const int cnt8 = (cnt + 7) & ~7;
    for (int jj = 0; jj < cnt8; jj += 8) {
        #pragma unroll
        for (int q = 0; q < 8; ++q) {
            const unsigned int pk = __shfl(pv, jj + q);
            const float m = b2f((unsigned short)(pk >> 16));
            const unsigned int u = xh32[bbase + (size_t)(pk & 0xFFFFu) * 64 + lane];
            union { unsigned int i; float f; } lo, hi;
            lo.i = u << 16;
            hi.i = u & 0xFFFF0000u;
            a0 = fmaf(lo.f, m, a0);
            a1 = fmaf(hi.f, m, a1);
            c += m;
        }
    }
    const float inv = 1.f / fmaxf(c, 1.f);
    nh32[(size_t)r * 64 + lane] = (unsigned int)f2b(a0 * inv) | ((unsigned int)f2b(a1 * inv) << 16);
}

// ---------------- fused layer v9: LDS-staged B; last layer emits pool partials ----------------
__global__ __launch_bounds__(256) void k_layer9(const unsigned short* __restrict__ xinh,
                                                const unsigned short* __restrict__ nh,
                                                const unsigned short* __restrict__ Bp,
                                                const float* __restrict__ sb,
                                                const float* __restrict__ nb,
                                                const float* __restrict__ lng,
                                                const float* __restrict__ lnb,
                                                const float* __restrict__ nmask,
                                                unsigned short* __restrict__ oxh,
                                                float* __restrict__ part,
                                                const int last) {
    __shared__ __align__(16) unsigned short bbuf[2][16 * 512];   // 2 x 16 KB
    __shared__ float lsum[2][64];
    __shared__ float lsq[2][64];
    __shared__ float psum_s[2][H];
    __shared__ float pmax_s[2][H];

    const int tid = threadIdx.x;
    const int wv = tid >> 6, lane = tid & 63;
    const int quad = lane >> 4, col = lane & 15;
    const int mg = wv >> 1, nw = wv & 1;
    const int u = blockIdx.x;
    const int b = u & 7;
    const int chunk = u >> 3;                     // 0..127
    const int row0 = b * N + chunk * 64;          // batch-pinned to XCD b

    size_t abase[2];
    #pragma unroll
    for (int mt = 0; mt < 2; ++mt)
        abase[mt] = (size_t)(row0 + (mg * 2 + mt) * 16 + col) * H + quad * 8;

    #pragma unroll
    for (int i = 0; i < 4; ++i) {
        const unsigned short* g = Bp + (size_t)(wv * 4 + i) * 512 + lane * 8;
        __builtin_amdgcn_global_load_lds((const AS1 unsigned int*)g,
                                         (AS3 unsigned int*)&bbuf[0][(wv * 4 + i) * 512],
                                         16, 0, 0);
    }
    bf16x8 aC[2][2];
    #pragma unroll
    for (int j = 0; j < 2; ++j)
        #pragma unroll
        for (int mt = 0; mt < 2; ++mt)
            aC[j][mt] = *(const bf16x8*)&xinh[abase[mt] + j * 32];

    f32x4 acc[2][4] = {};

    #pragma unroll
    for (int c = 0; c < 4; ++c) {
        __syncthreads();
        bf16x8 aN[2][2];
        if (c < 3) {
            const int c1 = c + 1;
            #pragma unroll
            for (int i = 0; i < 4; ++i) {
                const unsigned short* g = Bp + (size_t)(c1 * 16 + wv * 4 + i) * 512 + lane * 8;
                __builtin_amdgcn_global_load_lds((const AS1 unsigned int*)g,
                                                 (AS3 unsigned int*)&bbuf[c1 & 1][(wv * 4 + i) * 512],
                                                 16, 0, 0);
            }
            const unsigned short* A1 = (c1 < 2) ? xinh : nh;   // steps 0-3: xh, 4-7: nh
            #pragma unroll
            for (int j = 0; j < 2; ++j)
                #pragma unroll
                for (int mt = 0; mt < 2; ++mt)
                    aN[j][mt] = *(const bf16x8*)&A1[abase[mt] + ((c1 & 1) * 2 + j) * 32];
        }
        #pragma unroll
        for (int j = 0; j < 2; ++j) {
            bf16x8 bf[4];
            #pragma unroll
            for (int nt = 0; nt < 4; ++nt)
                bf[nt] = *(const bf16x8*)&bbuf[c & 1][(j * 8 + nw * 4 + nt) * 512 + lane * 8];
            #pragma unroll
            for (int mt = 0; mt < 2; ++mt)
                #pragma unroll
                for (int nt = 0; nt < 4; ++nt)
                    acc[mt][nt] = __builtin_amdgcn_mfma_f32_16x16x32_bf16(aC[j][mt], bf[nt], acc[mt][nt], 0, 0, 0);
        }
        #pragma unroll
        for (int j = 0; j < 2; ++j)
            #pragma unroll
            for (int mt = 0; mt < 2; ++mt)
                aC[j][mt] = aN[j][mt];
    }

    // bias + relu
    float sbv[4], nbv[4], gv[4], bbv[4];
    #pragma unroll
    for (int nt = 0; nt < 4; ++nt) {
        const int hh = (nw * 4 + nt) * 16 + col;
        sbv[nt] = sb[hh]; nbv[nt] = nb[hh]; gv[nt] = lng[hh]; bbv[nt] = lnb[hh];
    }
    #pragma unroll
    for (int mt = 0; mt < 2; ++mt)
        #pragma unroll
        for (int nt = 0; nt < 4; ++nt)
            #pragma unroll
            for (int r = 0; r < 4; ++r)
                acc[mt][nt][r] = fmaxf(acc[mt][nt][r] + sbv[nt] + nbv[nt], 0.f);

    // LN partials
    #pragma unroll
    for (int mt = 0; mt < 2; ++mt)
        #pragma unroll
        for (int r = 0; r < 4; ++r) {
            float p = 0.f, q = 0.f;
            #pragma unroll
            for (int nt = 0; nt < 4; ++nt) {
                const float v = acc[mt][nt][r];
                p += v;
                q = fmaf(v, v, q);
            }
            p += __shfl_xor(p, 1);  q += __shfl_xor(q, 1);
            p += __shfl_xor(p, 2);  q += __shfl_xor(q, 2);
            p += __shfl_xor(p, 4);  q += __shfl_xor(q, 4);
            p += __shfl_xor(p, 8);  q += __shfl_xor(q, 8);
            if (col == 0) {
                const int rib = (mg * 2 + mt) * 16 + quad * 4 + r;
                lsum[nw][rib] = p;
                lsq[nw][rib] = q;
            }
        }
    __syncthreads();   // all A-reads done before in-place stores

    float psum[4] = {0.f, 0.f, 0.f, 0.f};
    float pmax[4] = {-INFINITY, -INFINITY, -INFINITY, -INFINITY};

    #pragma unroll
    for (int mt = 0; mt < 2; ++mt)
        #pragma unroll
        for (int r = 0; r < 4; ++r) {
            const int rib = (mg * 2 + mt) * 16 + quad * 4 + r;
            const int node = row0 + rib;
            const float mu = (lsum[0][rib] + lsum[1][rib]) * (1.f / H);
            const float var = (lsq[0][rib] + lsq[1][rib]) * (1.f / H) - mu * mu;
            const float isd = rsqrtf(var + EPS);
            const float m = nmask[node];
            #pragma unroll
            for (int nt = 0; nt < 4; ++nt) {
                const float y = (fmaf(acc[mt][nt][r] - mu, isd * gv[nt], bbv[nt])) * m;
                if (!last) {
                    oxh[(size_t)node * H + (nw * 4 + nt) * 16 + col] = f2b(y);
                } else {
                    psum[nt] += y;
                    pmax[nt] = fmaxf(pmax[nt], (m > 0.f) ? y : -INFINITY);
                }
            }
        }

    if (last) {
        #pragma unroll
        for (int nt = 0; nt < 4; ++nt) {
            psum[nt] += __shfl_xor(psum[nt], 16);
            psum[nt] += __shfl_xor(psum[nt], 32);
            pmax[nt] = fmaxf(pmax[nt], __shfl_xor(pmax[nt], 16));
            pmax[nt] = fmaxf(pmax[nt], __shfl_xor(pmax[nt], 32));
        }
        if (quad == 0)
            #pragma unroll
            for (int nt = 0; nt < 4; ++nt) {
                psum_s[mg][(nw * 4 + nt) * 16 + col] = psum[nt];
                pmax_s[mg][(nw * 4 + nt) * 16 + col] = pmax[nt];
            }
        float nv = 0.f;
        if (wv == 0) {
            nv = nmask[row0 + lane];
            nv += __shfl_xor(nv, 1);  nv += __shfl_xor(nv, 2);
            nv += __shfl_xor(nv, 4);  nv += __shfl_xor(nv, 8);
            nv += __shfl_xor(nv, 16); nv += __shfl_xor(nv, 32);
        }
        __syncthreads();
        float* p = part + ((size_t)b * NCHUNK + chunk) * (2 * H + 1);
        if (tid < H) {
            p[tid] = psum_s[0][tid] + psum_s[1][tid];
            p[H + tid] = fmaxf(pmax_s[0][tid], pmax_s[1][tid]);
        }
        if (tid == 0) p[2 * H] = nv;
    }
}

// ---------------- fused pool-reduce + MLP head (parallelized: 1024 threads, 4-way chunk split) ----------------
__global__ __launch_bounds__(1024) void k_tail2(const float* __restrict__ part,
                                                const float* __restrict__ W1, const float* __restrict__ b1,
                                                const float* __restrict__ W2, const float* __restrict__ b2,
                                                float* __restrict__ out) {
    const int b = blockIdx.x, tid = threadIdx.x;
    const int col = tid & 255;          // 0..255: [0,H) sum-cols, [H,2H) max-cols
    const int sub = tid >> 8;           // 0..3: chunk quarter
    __shared__ float sred[4][2 * H];
    __shared__ float nvl[NCHUNK];
    __shared__ float g[2 * H];
    __shared__ float hid[H];

    // each sub reduces 32 chunks for its column; part layout per chunk: [sum H][max H][nv]
    {
        float acc = (col < H) ? 0.f : -INFINITY;
        #pragma unroll 8
        for (int c = sub * (NCHUNK / 4); c < (sub + 1) * (NCHUNK / 4); ++c) {
            const float v = part[((size_t)b * NCHUNK + c) * (2 * H + 1) + col];
            acc = (col < H) ? (acc + v) : fmaxf(acc, v);
        }
        sred[sub][col] = acc;
    }
    if (tid < NCHUNK)
        nvl[tid] = part[((size_t)b * NCHUNK + tid) * (2 * H + 1) + 2 * H];
    __syncthreads();
    // nv tree-reduce (128 -> 1)
    for (int s = NCHUNK / 2; s > 0; s >>= 1) {
        if (tid < s) nvl[tid] += nvl[tid + s];
        __syncthreads();
    }
    const float nv = fmaxf(nvl[0], 1.f);
    if (tid < 2 * H) {
        if (tid < H)
            g[tid] = (sred[0][tid] + sred[1][tid] + sred[2][tid] + sred[3][tid]) / nv;
        else
            g[tid] = fmaxf(fmaxf(sred[0][tid], sred[1][tid]), fmaxf(sred[2][tid], sred[3][tid]));
    }
    __syncthreads();
    if (tid < H) {
        float a = b1[tid];
        #pragma unroll 8
        for (int k = 0; k < 2 * H; ++k) a = fmaf(g[k], W1[k * H + tid], a);
        hid[tid] = fmaxf(a, 0.f);
    }
    __syncthreads();
    if (tid < OUTD) {
        float a = b2[tid];
        #pragma unroll 8
        for (int k = 0; k < H; ++k) a = fmaf(hid[k], W2[k * OUTD + tid], a);
        out[(size_t)b * OUTD + tid] = a;
    }
}

extern "C" void kernel_launch(void* const* d_in, const int* in_sizes, int n_in,
                              void* d_out, int out_size, void* d_ws, size_t ws_size,
                              hipStream_t stream) {
    const float* feats = (const float*)d_in[0];
    const int*   ei    = (const int*)d_in[1];
    const float* nmask = (const float*)d_in[2];
    const float* emask = (const float*)d_in[3];
    const float* inW   = (const float*)d_in[4];
    const float* inb   = (const float*)d_in[5];
    const float* selfW = (const float*)d_in[6];
    const float* selfb = (const float*)d_in[7];
    const float* neighW= (const float*)d_in[8];
    const float* neighb= (const float*)d_in[9];
    const float* lng   = (const float*)d_in[10];
    const float* lnb   = (const float*)d_in[11];
    const float* W1    = (const float*)d_in[12];
    const float* b1    = (const float*)d_in[13];
    const float* W2    = (const float*)d_in[14];
    const float* b2    = (const float*)d_in[15];
    float* out = (float*)d_out;

    const size_t nxh = (size_t)NNODE * H;
    char* w = (char*)d_ws;
    unsigned short* xh  = (unsigned short*)w;  w += nxh * 2;
    unsigned short* nh  = (unsigned short*)w;  w += nxh * 2;
    unsigned short* Bp  = (unsigned short*)w;  w += (size_t)NLAYER * BPL * 2;
    unsigned short* Bpi = (unsigned short*)w;  w += (size_t)INSTEPS * 8 * 512 * 2;
    float* part = (float*)w;                   w += (size_t)B * NCHUNK * (2 * H + 1) * 4;
    int* ecnt   = (int*)w;                     w += (size_t)NNODE * 4;
    unsigned int* ell = (unsigned int*)w;      w += (size_t)NNODE * ELLW * 4;

    k_prep<<<NLAYER * KSTEPS * 8 + INSTEPS * 8, 64, 0, stream>>>(selfW, neighW, inW, Bp, Bpi);
    hipMemsetAsync(ecnt, 0, (size_t)NNODE * sizeof(int), stream);
    k_front<<<1024 + B * E / 256, 256, 0, stream>>>(feats, Bpi, inb, xh, ei, emask, ecnt, ell);

    for (int l = 0; l < NLAYER; ++l) {
        k_gather7<<<NNODE / 4, 256, 0, stream>>>((const unsigned int*)xh, ecnt, ell,
                                                 (unsigned int*)nh);
        k_layer9<<<NNODE / 64, 256, 0, stream>>>(xh, nh,
                                                 Bp + (size_t)l * BPL,
                                                 selfb + (size_t)l * H, neighb + (size_t)l * H,
                                                 lng + (size_t)l * H, lnb + (size_t)l * H,
                                                 nmask, xh, part, (l == NLAYER - 1) ? 1 : 0);
    }

    k_tail2<<<B, 1024, 0, stream>>>(part, W1, b1, W2, b2, out);
}